// Round 1
// baseline (365.642 us; speedup 1.0000x reference)
//
#include <hip/hip_runtime.h>
#include <math.h>

// ---------------------------------------------------------------------------
// GIN, 3 layers, N=100000, E=1000000, D=64, fp32 in/out.
// Round 11: dispatch-count attack. 13 kernels -> 7:
//   - gather fused into the MLP kernel (per-wave: gather 16 nodes into the
//     wave-private LDS tile, then MFMA phases). Removes the fp32 agg global
//     round-trip (~51 MB/layer) and 3 kernel boundaries. Activations are
//     double-buffered (xb0/xb1) since gather-read and MLP-write now coexist
//     in one kernel.
//   - k_cvt + k_cnt + k_pack_all merged into one heterogeneous launch.
//   - k_scanB dropped: k_place scans the 782 bintotals locally in LDS
//     (3 KB read, trivial) and block 0 publishes binstart for k_binsort.
// Numerics unchanged from round 10 (bf16 rows, fp32 gather accum, bf16 hi/lo
// 3-MFMA MLP).
// ---------------------------------------------------------------------------

#define FEAT  64
#define BINW  128          // nodes per bin
#define BSH   7            // log2(BINW)
#define NBLK  256          // edge-partition blocks
#define SRCB  25           // bits for src in packed key (N < 2^25)

typedef __attribute__((ext_vector_type(8))) short bfrag;   // 8 bf16 (4 VGPRs)
typedef __attribute__((ext_vector_type(4))) float ffrag;   // 4 fp32 acc

__device__ __forceinline__ unsigned short f2bf_rne(float x) {
    union { float f; unsigned u; } v; v.f = x;
    unsigned r = (v.u + 0x7fffu + ((v.u >> 16) & 1u)) >> 16;
    return (unsigned short)r;
}
__device__ __forceinline__ float bf2f(unsigned short h) {
    union { unsigned u; float f; } v; v.u = ((unsigned)h) << 16;
    return v.f;
}

// ---------------- weight pack helper ---------------------------------------
__device__ __forceinline__ void pack_one(const float* __restrict__ w,
                                         unsigned short* __restrict__ hi,
                                         unsigned short* __restrict__ lo,
                                         int K, int Hc, int i) {
    int KF = K >> 5;
    int j    = i & 7;
    int lane = (i >> 3) & 63;
    int fb   = i >> 9;
    int kf   = fb % KF;
    int cg   = fb / KF;
    int k    = kf * 32 + ((lane >> 4) << 3) + j;
    int col  = cg * 16 + (lane & 15);
    float x = w[k * Hc + col];
    unsigned short h = f2bf_rne(x);
    hi[i] = h;
    lo[i] = f2bf_rne(x - bf2f(h));
}

// ---------------- pre: cvt + cnt + pack, one launch ------------------------
// blocks [0, gCvt): x -> bf16 rows
// blocks [gCvt, gCvt+NBLK): per-block bin histogram (counts[bin*NBLK + b])
// blocks [gCvt+NBLK, +128): pack all 6 weight matrices (bf16 hi/lo, frag order)
__global__ __launch_bounds__(256)
void k_pre(const float4* __restrict__ x4, ushort4* __restrict__ xb4,
           int n4, int gCvt,
           const int* __restrict__ dst, int* __restrict__ counts,
           int E, int NBINS,
           const float* w11, const float* w12, const float* w21,
           const float* w22, const float* w31, const float* w32,
           unsigned short* p11h, unsigned short* p11l,
           unsigned short* p12h, unsigned short* p12l,
           unsigned short* p21h, unsigned short* p21l,
           unsigned short* p22h, unsigned short* p22l,
           unsigned short* p31h, unsigned short* p31l,
           unsigned short* p32h, unsigned short* p32l) {
    __shared__ int h[1024];
    const int bb = blockIdx.x, tid = threadIdx.x;
    if (bb < gCvt) {
        int i = bb * 256 + tid;
        if (i < n4) {
            float4 v = x4[i];
            ushort4 o;
            o.x = f2bf_rne(v.x); o.y = f2bf_rne(v.y);
            o.z = f2bf_rne(v.z); o.w = f2bf_rne(v.w);
            xb4[i] = o;
        }
    } else if (bb < gCvt + NBLK) {
        const int b = bb - gCvt;
        for (int i = tid; i < NBINS; i += 256) h[i] = 0;
        __syncthreads();
        const int chunk = (E + NBLK - 1) / NBLK;
        const int ebeg = b * chunk;
        const int eend = (ebeg + chunk < E) ? ebeg + chunk : E;
        for (int e = ebeg + tid; e < eend; e += 256)
            atomicAdd(&h[dst[e] >> BSH], 1);          // LDS atomic
        __syncthreads();
        for (int i = tid; i < NBINS; i += 256)
            counts[i * NBLK + b] = h[i];
    } else {
        int i = (bb - gCvt - NBLK) * 256 + tid;       // 0..32767
        if      (i <  4096) pack_one(w11, p11h, p11l,  64,  64, i);
        else if (i <  8192) pack_one(w12, p12h, p12l,  64,  64, i - 4096);
        else if (i < 16384) pack_one(w21, p21h, p21l,  64, 128, i - 8192);
        else if (i < 24576) pack_one(w22, p22h, p22l, 128,  64, i - 16384);
        else if (i < 28672) pack_one(w31, p31h, p31l,  64,  64, i - 24576);
        else                pack_one(w32, p32h, p32l,  64,  64, i - 28672);
    }
}

// ---------------- per-bin scan over the 256 partition blocks ---------------
__global__ __launch_bounds__(256)
void k_scanA2(int* __restrict__ counts, int* __restrict__ bintotal,
              int* __restrict__ rowptr, int NBINS, int N, int E) {
    __shared__ int tmp[256];
    const int bin = blockIdx.x, tid = threadIdx.x;
    int c = counts[bin * NBLK + tid];
    tmp[tid] = c;
    __syncthreads();
    for (int off = 1; off < 256; off <<= 1) {
        int t = (tid >= off) ? tmp[tid - off] : 0;
        __syncthreads();
        tmp[tid] += t;
        __syncthreads();
    }
    counts[bin * NBLK + tid] = tmp[tid] - c;      // exclusive within bin
    if (tid == 255) bintotal[bin] = tmp[255];
    if (bin == 0 && tid == 0) rowptr[N] = E;
}

// ---------------- place edges (local binstart scan, no scanB) --------------
__global__ __launch_bounds__(256)
void k_place2(const int* __restrict__ src, const int* __restrict__ dst,
              const float* __restrict__ ew, const int* __restrict__ counts,
              const int* __restrict__ bintotal, int* __restrict__ binstart,
              int2* __restrict__ binbuf, int E, int NBINS) {
    __shared__ int bs[1024];        // local exclusive prefix of bintotal
    __shared__ int tmp[256];
    __shared__ int base[1024];
    const int b = blockIdx.x, tid = threadIdx.x;

    // blocked exclusive scan of bintotal[0..NBINS) (4 elems/thread)
    int v[4]; int s = 0;
#pragma unroll
    for (int j = 0; j < 4; ++j) {
        int idx = tid * 4 + j;
        v[j] = (idx < NBINS) ? bintotal[idx] : 0;
        s += v[j];
    }
    tmp[tid] = s;
    __syncthreads();
    for (int off = 1; off < 256; off <<= 1) {
        int t = (tid >= off) ? tmp[tid - off] : 0;
        __syncthreads();
        tmp[tid] += t;
        __syncthreads();
    }
    int run = tmp[tid] - s;         // exclusive across thread chunks
#pragma unroll
    for (int j = 0; j < 4; ++j) {
        bs[tid * 4 + j] = run;
        run += v[j];
    }
    __syncthreads();

    // block 0 publishes binstart for k_binsort
    if (b == 0) {
        for (int i = tid; i < NBINS; i += 256) binstart[i] = bs[i];
        if (tid == 0) binstart[NBINS] = E;
    }

    for (int i = tid; i < NBINS; i += 256)
        base[i] = bs[i] + counts[i * NBLK + b];
    __syncthreads();

    const int chunk = (E + NBLK - 1) / NBLK;
    const int ebeg = b * chunk;
    const int eend = (ebeg + chunk < E) ? ebeg + chunk : E;
    for (int e = ebeg + tid; e < eend; e += 256) {
        int d = dst[e];
        int slot = atomicAdd(&base[d >> BSH], 1);   // LDS atomic only
        int key = ((d & (BINW - 1)) << SRCB) | src[e];
        binbuf[slot] = make_int2(key, __float_as_int(ew[e]));
    }
}

// one block per bin: count 128 nodes -> scan -> rowptr -> place edges.
__global__ __launch_bounds__(256)
void k_binsort(const int2* __restrict__ binbuf, const int* __restrict__ binstart,
               int* __restrict__ rowptr, int2* __restrict__ csr, int N) {
    __shared__ int cnt[BINW];
    __shared__ int cur[BINW];
    const int b    = blockIdx.x;
    const int base = binstart[b];
    const int ne   = binstart[b + 1] - base;
    const int tid  = threadIdx.x;

    if (tid < BINW) cnt[tid] = 0;
    __syncthreads();
    for (int i = tid; i < ne; i += 256)
        atomicAdd(&cnt[(binbuf[base + i].x >> SRCB) & (BINW - 1)], 1);
    __syncthreads();
    if (tid < BINW) cur[tid] = cnt[tid];
    __syncthreads();
    for (int off = 1; off < BINW; off <<= 1) {
        int v = (tid < BINW && tid >= off) ? cur[tid - off] : 0;
        __syncthreads();
        if (tid < BINW) cur[tid] += v;
        __syncthreads();
    }
    if (tid < BINW) {
        int ex = cur[tid] - cnt[tid];          // exclusive within bin
        int node = b * BINW + tid;
        if (node < N) rowptr[node] = base + ex;
        cur[tid] = ex;                         // cursor
    }
    __syncthreads();
    for (int i = tid; i < ne; i += 256) {
        int2 e = binbuf[base + i];
        int dl = (e.x >> SRCB) & (BINW - 1);
        int r = atomicAdd(&cur[dl], 1);
        csr[base + r] = make_int2(e.x & ((1 << SRCB) - 1), e.y);
    }
}

// ---------------- fused gather + MLP ---------------------------------------
// Block = 4 waves, 64 nodes. Each wave owns 16 nodes end-to-end:
//   gather phase: per node, 4 edge-slots(q) x 16 feature-quads(m), 16 edges/
//   iter, fp32 accum, +x, result -> wave-private LDS tile (row=node, col=feat)
//   MLP phase: A-frags (bf16 hi/lo) from LDS, phase-1 h=relu(A@W1+b1) back to
//   the same tile, phase-2 out=h@W2+b2.
// in and out MUST be different buffers (gather reads arbitrary rows of `in`
// while other blocks write `out`).
template<int H, bool RELU_OUT, bool OUT_BF16>
__global__ __launch_bounds__(256)
void k_fused(const ushort* __restrict__ in, void* __restrict__ outv,
             const int* __restrict__ rowptr, const int2* __restrict__ csr,
             const unsigned short* __restrict__ w1h, const unsigned short* __restrict__ w1l,
             const float* __restrict__ b1,
             const unsigned short* __restrict__ w2h, const unsigned short* __restrict__ w2l,
             const float* __restrict__ b2, int N) {
    constexpr int SH  = H + 4;      // LDS h-row stride: 2-way bank alias only
    constexpr int CG1 = H / 16;     // phase-1 col groups
    constexpr int KF2 = H / 32;     // phase-2 k frags
    __shared__ float hs[4 * 16 * SH];

    const int t = threadIdx.x;
    const int wv = t >> 6, lane = t & 63;
    const int m = lane & 15, q = lane >> 4;   // m: feat-quad / node-in-16; q: slot / k-half
    const int node0 = blockIdx.x * 64 + wv * 16;
    float* hw = &hs[wv * 16 * SH];
    const ushort4* in4 = reinterpret_cast<const ushort4*>(in);

    // ---- gather: 16 nodes, wave-private; tile row n gets agg+x of node0+n ----
    for (int n = 0; n < 16; ++n) {
        const int node = node0 + n;
        float4 acc = make_float4(0.f, 0.f, 0.f, 0.f);
        if (node < N) {                        // wave-uniform branch
            const int beg = rowptr[node];
            const int end = rowptr[node + 1];
            ushort4 xr4 = in4[(size_t)node * 16 + m];   // "+x", issue early
            for (int p = beg; p < end; p += 16) {
                int   s[4];
                float w[4];
#pragma unroll
                for (int u = 0; u < 4; ++u) {
                    int i = p + 4 * u + q;
                    int2 ev = make_int2(0, 0);
                    if (i < end) ev = csr[i];        // broadcast in 16-lane group
                    s[u] = ev.x;
                    w[u] = __int_as_float(ev.y);     // 0.0f when inactive
                }
                ushort4 v4[4];
#pragma unroll
                for (int u = 0; u < 4; ++u)
                    v4[u] = in4[(size_t)s[u] * 16 + m];  // 4 row-loads in flight
#pragma unroll
                for (int u = 0; u < 4; ++u) {
                    acc.x = fmaf(w[u], bf2f(v4[u].x), acc.x);
                    acc.y = fmaf(w[u], bf2f(v4[u].y), acc.y);
                    acc.z = fmaf(w[u], bf2f(v4[u].z), acc.z);
                    acc.w = fmaf(w[u], bf2f(v4[u].w), acc.w);
                }
            }
            // butterfly across the 4 edge-slots (lane bits 4,5)
            acc.x += __shfl_xor(acc.x, 16); acc.y += __shfl_xor(acc.y, 16);
            acc.z += __shfl_xor(acc.z, 16); acc.w += __shfl_xor(acc.w, 16);
            acc.x += __shfl_xor(acc.x, 32); acc.y += __shfl_xor(acc.y, 32);
            acc.z += __shfl_xor(acc.z, 32); acc.w += __shfl_xor(acc.w, 32);
            acc.x += bf2f(xr4.x); acc.y += bf2f(xr4.y);
            acc.z += bf2f(xr4.z); acc.w += bf2f(xr4.w);
        }
        if (q == 0)
            *reinterpret_cast<float4*>(&hw[n * SH + m * 4]) = acc;  // zeros for pad nodes
    }
    __syncthreads();   // cheap; guards LDS write->read ordering

    // ---- A frags (K=64 -> 2 kf) from LDS, split hi/lo ----
    const bfrag* w1hp = reinterpret_cast<const bfrag*>(w1h);
    const bfrag* w1lp = reinterpret_cast<const bfrag*>(w1l);
    const bfrag* w2hp = reinterpret_cast<const bfrag*>(w2h);
    const bfrag* w2lp = reinterpret_cast<const bfrag*>(w2l);

    bfrag ah[2], al[2];
#pragma unroll
    for (int kf = 0; kf < 2; ++kf) {
        const float* base = &hw[m * SH + kf * 32 + q * 8];
        float4 u0 = *reinterpret_cast<const float4*>(base);
        float4 u1 = *reinterpret_cast<const float4*>(base + 4);
        float u[8] = {u0.x, u0.y, u0.z, u0.w, u1.x, u1.y, u1.z, u1.w};
#pragma unroll
        for (int j = 0; j < 8; ++j) {
            unsigned short hb = f2bf_rne(u[j]);
            ah[kf][j] = (short)hb;
            al[kf][j] = (short)f2bf_rne(u[j] - bf2f(hb));
        }
    }
    __syncthreads();

    // ---- phase 1: h = relu(A@W1 + b1) -> LDS (wave-private tile) ----
#pragma unroll
    for (int cg = 0; cg < CG1; ++cg) {
        ffrag c = {0.f, 0.f, 0.f, 0.f};
#pragma unroll
        for (int kf = 0; kf < 2; ++kf) {
            bfrag bh = w1hp[(cg * 2 + kf) * 64 + lane];
            bfrag bl = w1lp[(cg * 2 + kf) * 64 + lane];
            c = __builtin_amdgcn_mfma_f32_16x16x32_bf16(ah[kf], bh, c, 0, 0, 0);
            c = __builtin_amdgcn_mfma_f32_16x16x32_bf16(al[kf], bh, c, 0, 0, 0);
            c = __builtin_amdgcn_mfma_f32_16x16x32_bf16(ah[kf], bl, c, 0, 0, 0);
        }
        float bias = b1[cg * 16 + m];
#pragma unroll
        for (int r = 0; r < 4; ++r) {
            float hv = fmaxf(c[r] + bias, 0.f);
            hw[(q * 4 + r) * SH + cg * 16 + m] = hv;   // row=node, col=h-col
        }
    }
    __syncthreads();

    // ---- h -> A frags (hi/lo) ----
    bfrag gh[KF2], gl[KF2];
#pragma unroll
    for (int kf = 0; kf < KF2; ++kf) {
        const float* base = &hw[m * SH + kf * 32 + q * 8];
        float4 u0 = *reinterpret_cast<const float4*>(base);
        float4 u1 = *reinterpret_cast<const float4*>(base + 4);
        float u[8] = {u0.x, u0.y, u0.z, u0.w, u1.x, u1.y, u1.z, u1.w};
#pragma unroll
        for (int j = 0; j < 8; ++j) {
            unsigned short hb = f2bf_rne(u[j]);
            gh[kf][j] = (short)hb;
            gl[kf][j] = (short)f2bf_rne(u[j] - bf2f(hb));
        }
    }

    // ---- phase 2: out = h@W2 + b2 ----
#pragma unroll
    for (int cg = 0; cg < 4; ++cg) {
        ffrag c = {0.f, 0.f, 0.f, 0.f};
#pragma unroll
        for (int kf = 0; kf < KF2; ++kf) {
            bfrag bh = w2hp[(cg * KF2 + kf) * 64 + lane];
            bfrag bl = w2lp[(cg * KF2 + kf) * 64 + lane];
            c = __builtin_amdgcn_mfma_f32_16x16x32_bf16(gh[kf], bh, c, 0, 0, 0);
            c = __builtin_amdgcn_mfma_f32_16x16x32_bf16(gl[kf], bh, c, 0, 0, 0);
            c = __builtin_amdgcn_mfma_f32_16x16x32_bf16(gh[kf], bl, c, 0, 0, 0);
        }
        float bias = b2[cg * 16 + m];
#pragma unroll
        for (int r = 0; r < 4; ++r) {
            int nd = node0 + q * 4 + r;
            if (nd < N) {
                float v = c[r] + bias;
                if (RELU_OUT) v = fmaxf(v, 0.f);
                if (OUT_BF16)
                    ((unsigned short*)outv)[(size_t)nd * FEAT + cg * 16 + m] = f2bf_rne(v);
                else
                    ((float*)outv)[(size_t)nd * FEAT + cg * 16 + m] = v;
            }
        }
    }
}

// ---------------------------------------------------------------------------
extern "C" void kernel_launch(void* const* d_in, const int* in_sizes, int n_in,
                              void* d_out, int out_size, void* d_ws, size_t ws_size,
                              hipStream_t stream) {
    const float* x   = (const float*)d_in[0];
    const int*   ei  = (const int*)  d_in[1];
    const float* ew  = (const float*)d_in[2];
    const float* w11 = (const float*)d_in[3];
    const float* b11 = (const float*)d_in[4];
    const float* w12 = (const float*)d_in[5];
    const float* b12 = (const float*)d_in[6];
    const float* w21 = (const float*)d_in[7];
    const float* b21 = (const float*)d_in[8];
    const float* w22 = (const float*)d_in[9];
    const float* b22 = (const float*)d_in[10];
    const float* w31 = (const float*)d_in[11];
    const float* b31 = (const float*)d_in[12];
    const float* w32 = (const float*)d_in[13];
    const float* b32 = (const float*)d_in[14];

    const int N = in_sizes[0] / FEAT;   // 100000
    const int E = in_sizes[2];          // 1000000
    const int* srci = ei;
    const int* dsti = ei + E;
    const int NBINS = (N + BINW - 1) >> BSH;   // 782

    // ---- workspace layout ----
    unsigned short* xb0 = (unsigned short*)d_ws;             // [N*64] bf16
    unsigned short* xb1 = xb0 + (size_t)N * FEAT;            // [N*64] bf16
    int*   rowptr   = (int*)(xb1 + (size_t)N * FEAT);        // [N+1]
    int*   counts   = rowptr + (N + 1);                      // [NBINS*NBLK]
    int*   bintotal = counts + NBINS * NBLK;                 // [NBINS]
    int*   binstart = bintotal + NBINS;                      // [NBINS+1]
    size_t a16 = ((size_t)(binstart + NBINS + 1) + 15) & ~(size_t)15;
    int2*  binbuf   = (int2*)a16;                            // [E] (key, w)
    int2*  csr      = (int2*)(binbuf + E);                   // [E] (src, w)
    size_t pk = (size_t)(csr + E);
    unsigned short* p11h = (unsigned short*)pk;              // 4096 each for 64x64
    unsigned short* p11l = p11h + 4096;
    unsigned short* p12h = p11l + 4096;
    unsigned short* p12l = p12h + 4096;
    unsigned short* p21h = p12l + 4096;                      // 8192 for 64x128
    unsigned short* p21l = p21h + 8192;
    unsigned short* p22h = p21l + 8192;                      // 8192 for 128x64
    unsigned short* p22l = p22h + 8192;
    unsigned short* p31h = p22l + 8192;
    unsigned short* p31l = p31h + 4096;
    unsigned short* p32h = p31l + 4096;
    unsigned short* p32l = p32h + 4096;
    float* outF = (float*)d_out;                             // [N*64]

    const int n4   = N * 16;
    const int gCvt = (n4 + 255) / 256;
    const int gMlp = (N + 63) / 64;
    const int gPre = gCvt + NBLK + 128;

    // ---- pre: cvt + histogram + weight pack (one launch) ----
    k_pre<<<gPre, 256, 0, stream>>>((const float4*)x, (ushort4*)xb0, n4, gCvt,
                                    dsti, counts, E, NBINS,
                                    w11, w12, w21, w22, w31, w32,
                                    p11h, p11l, p12h, p12l, p21h, p21l,
                                    p22h, p22l, p31h, p31l, p32h, p32l);
    // ---- CSR build (scanB folded into place) ----
    k_scanA2 <<<NBINS, 256, 0, stream>>>(counts, bintotal, rowptr, NBINS, N, E);
    k_place2 <<<NBLK,  256, 0, stream>>>(srci, dsti, ew, counts, bintotal,
                                         binstart, binbuf, E, NBINS);
    k_binsort<<<NBINS, 256, 0, stream>>>(binbuf, binstart, rowptr, csr, N);

    // ---- fused layers (double-buffered activations) ----
    k_fused<64,  true,  true ><<<gMlp, 256, 0, stream>>>(xb0, xb1, rowptr, csr,
                                                         p11h, p11l, b11, p12h, p12l, b12, N);
    k_fused<128, true,  true ><<<gMlp, 256, 0, stream>>>(xb1, xb0, rowptr, csr,
                                                         p21h, p21l, b21, p22h, p22l, b22, N);
    k_fused<64,  false, false><<<gMlp, 256, 0, stream>>>(xb0, outF, rowptr, csr,
                                                         p31h, p31l, b31, p32h, p32l, b32, N);
}

// Round 3
// 319.823 us; speedup vs baseline: 1.1433x; 1.1433x over previous
//
#include <hip/hip_runtime.h>
#include <math.h>

// ---------------------------------------------------------------------------
// GIN, 3 layers, N=100000, E=1000000, D=64, fp32 in/out.
// Round 12b: gather-parallelism fix inside the fused kernel (compile fix of
// round 12: restored the dropped p32l declaration).
//   Round-11 post-mortem: fused kernel was latency-bound (VALU 25%, MFMA 4%,
//   HBM 10%) because each wave serially walked 16 nodes (avg degree 10) with
//   only 4 row-loads in flight and a dependent rowptr->csr->row chain per
//   node. Fix:
//     - one node per 16-lane group (4 nodes in parallel per wave), 4 edges
//       in flight per group -> 16 row-loads in flight per wave (4x MLP),
//       and no cross-lane butterfly needed at all.
//     - rowptr boundaries for the wave's 16 nodes preloaded lane-parallel
//       (one load), broadcast via __shfl.
//     - "+x" rows for all 4 batches hoisted ahead of the edge loops.
//     - both __syncthreads() removed: the LDS tile is wave-private and LDS
//       ops are in-order within a wave; waves fully decoupled.
//   Everything else (CSR build, pre-kernel, MLP phases) unchanged from R11.
// ---------------------------------------------------------------------------

#define FEAT  64
#define BINW  128          // nodes per bin
#define BSH   7            // log2(BINW)
#define NBLK  256          // edge-partition blocks
#define SRCB  25           // bits for src in packed key (N < 2^25)

typedef __attribute__((ext_vector_type(8))) short bfrag;   // 8 bf16 (4 VGPRs)
typedef __attribute__((ext_vector_type(4))) float ffrag;   // 4 fp32 acc

__device__ __forceinline__ unsigned short f2bf_rne(float x) {
    union { float f; unsigned u; } v; v.f = x;
    unsigned r = (v.u + 0x7fffu + ((v.u >> 16) & 1u)) >> 16;
    return (unsigned short)r;
}
__device__ __forceinline__ float bf2f(unsigned short h) {
    union { unsigned u; float f; } v; v.u = ((unsigned)h) << 16;
    return v.f;
}

// ---------------- weight pack helper ---------------------------------------
__device__ __forceinline__ void pack_one(const float* __restrict__ w,
                                         unsigned short* __restrict__ hi,
                                         unsigned short* __restrict__ lo,
                                         int K, int Hc, int i) {
    int KF = K >> 5;
    int j    = i & 7;
    int lane = (i >> 3) & 63;
    int fb   = i >> 9;
    int kf   = fb % KF;
    int cg   = fb / KF;
    int k    = kf * 32 + ((lane >> 4) << 3) + j;
    int col  = cg * 16 + (lane & 15);
    float x = w[k * Hc + col];
    unsigned short h = f2bf_rne(x);
    hi[i] = h;
    lo[i] = f2bf_rne(x - bf2f(h));
}

// ---------------- pre: cvt + cnt + pack, one launch ------------------------
__global__ __launch_bounds__(256)
void k_pre(const float4* __restrict__ x4, ushort4* __restrict__ xb4,
           int n4, int gCvt,
           const int* __restrict__ dst, int* __restrict__ counts,
           int E, int NBINS,
           const float* w11, const float* w12, const float* w21,
           const float* w22, const float* w31, const float* w32,
           unsigned short* p11h, unsigned short* p11l,
           unsigned short* p12h, unsigned short* p12l,
           unsigned short* p21h, unsigned short* p21l,
           unsigned short* p22h, unsigned short* p22l,
           unsigned short* p31h, unsigned short* p31l,
           unsigned short* p32h, unsigned short* p32l) {
    __shared__ int h[1024];
    const int bb = blockIdx.x, tid = threadIdx.x;
    if (bb < gCvt) {
        int i = bb * 256 + tid;
        if (i < n4) {
            float4 v = x4[i];
            ushort4 o;
            o.x = f2bf_rne(v.x); o.y = f2bf_rne(v.y);
            o.z = f2bf_rne(v.z); o.w = f2bf_rne(v.w);
            xb4[i] = o;
        }
    } else if (bb < gCvt + NBLK) {
        const int b = bb - gCvt;
        for (int i = tid; i < NBINS; i += 256) h[i] = 0;
        __syncthreads();
        const int chunk = (E + NBLK - 1) / NBLK;
        const int ebeg = b * chunk;
        const int eend = (ebeg + chunk < E) ? ebeg + chunk : E;
        for (int e = ebeg + tid; e < eend; e += 256)
            atomicAdd(&h[dst[e] >> BSH], 1);          // LDS atomic
        __syncthreads();
        for (int i = tid; i < NBINS; i += 256)
            counts[i * NBLK + b] = h[i];
    } else {
        int i = (bb - gCvt - NBLK) * 256 + tid;       // 0..32767
        if      (i <  4096) pack_one(w11, p11h, p11l,  64,  64, i);
        else if (i <  8192) pack_one(w12, p12h, p12l,  64,  64, i - 4096);
        else if (i < 16384) pack_one(w21, p21h, p21l,  64, 128, i - 8192);
        else if (i < 24576) pack_one(w22, p22h, p22l, 128,  64, i - 16384);
        else if (i < 28672) pack_one(w31, p31h, p31l,  64,  64, i - 24576);
        else                pack_one(w32, p32h, p32l,  64,  64, i - 28672);
    }
}

// ---------------- per-bin scan over the 256 partition blocks ---------------
__global__ __launch_bounds__(256)
void k_scanA2(int* __restrict__ counts, int* __restrict__ bintotal,
              int* __restrict__ rowptr, int NBINS, int N, int E) {
    __shared__ int tmp[256];
    const int bin = blockIdx.x, tid = threadIdx.x;
    int c = counts[bin * NBLK + tid];
    tmp[tid] = c;
    __syncthreads();
    for (int off = 1; off < 256; off <<= 1) {
        int t = (tid >= off) ? tmp[tid - off] : 0;
        __syncthreads();
        tmp[tid] += t;
        __syncthreads();
    }
    counts[bin * NBLK + tid] = tmp[tid] - c;      // exclusive within bin
    if (tid == 255) bintotal[bin] = tmp[255];
    if (bin == 0 && tid == 0) rowptr[N] = E;
}

// ---------------- place edges (local binstart scan, no scanB) --------------
__global__ __launch_bounds__(256)
void k_place2(const int* __restrict__ src, const int* __restrict__ dst,
              const float* __restrict__ ew, const int* __restrict__ counts,
              const int* __restrict__ bintotal, int* __restrict__ binstart,
              int2* __restrict__ binbuf, int E, int NBINS) {
    __shared__ int bs[1024];        // local exclusive prefix of bintotal
    __shared__ int tmp[256];
    __shared__ int base[1024];
    const int b = blockIdx.x, tid = threadIdx.x;

    int v[4]; int s = 0;
#pragma unroll
    for (int j = 0; j < 4; ++j) {
        int idx = tid * 4 + j;
        v[j] = (idx < NBINS) ? bintotal[idx] : 0;
        s += v[j];
    }
    tmp[tid] = s;
    __syncthreads();
    for (int off = 1; off < 256; off <<= 1) {
        int t = (tid >= off) ? tmp[tid - off] : 0;
        __syncthreads();
        tmp[tid] += t;
        __syncthreads();
    }
    int run = tmp[tid] - s;
#pragma unroll
    for (int j = 0; j < 4; ++j) {
        bs[tid * 4 + j] = run;
        run += v[j];
    }
    __syncthreads();

    if (b == 0) {
        for (int i = tid; i < NBINS; i += 256) binstart[i] = bs[i];
        if (tid == 0) binstart[NBINS] = E;
    }

    for (int i = tid; i < NBINS; i += 256)
        base[i] = bs[i] + counts[i * NBLK + b];
    __syncthreads();

    const int chunk = (E + NBLK - 1) / NBLK;
    const int ebeg = b * chunk;
    const int eend = (ebeg + chunk < E) ? ebeg + chunk : E;
    for (int e = ebeg + tid; e < eend; e += 256) {
        int d = dst[e];
        int slot = atomicAdd(&base[d >> BSH], 1);   // LDS atomic only
        int key = ((d & (BINW - 1)) << SRCB) | src[e];
        binbuf[slot] = make_int2(key, __float_as_int(ew[e]));
    }
}

// one block per bin: count 128 nodes -> scan -> rowptr -> place edges.
__global__ __launch_bounds__(256)
void k_binsort(const int2* __restrict__ binbuf, const int* __restrict__ binstart,
               int* __restrict__ rowptr, int2* __restrict__ csr, int N) {
    __shared__ int cnt[BINW];
    __shared__ int cur[BINW];
    const int b    = blockIdx.x;
    const int base = binstart[b];
    const int ne   = binstart[b + 1] - base;
    const int tid  = threadIdx.x;

    if (tid < BINW) cnt[tid] = 0;
    __syncthreads();
    for (int i = tid; i < ne; i += 256)
        atomicAdd(&cnt[(binbuf[base + i].x >> SRCB) & (BINW - 1)], 1);
    __syncthreads();
    if (tid < BINW) cur[tid] = cnt[tid];
    __syncthreads();
    for (int off = 1; off < BINW; off <<= 1) {
        int v = (tid < BINW && tid >= off) ? cur[tid - off] : 0;
        __syncthreads();
        if (tid < BINW) cur[tid] += v;
        __syncthreads();
    }
    if (tid < BINW) {
        int ex = cur[tid] - cnt[tid];
        int node = b * BINW + tid;
        if (node < N) rowptr[node] = base + ex;
        cur[tid] = ex;
    }
    __syncthreads();
    for (int i = tid; i < ne; i += 256) {
        int2 e = binbuf[base + i];
        int dl = (e.x >> SRCB) & (BINW - 1);
        int r = atomicAdd(&cur[dl], 1);
        csr[base + r] = make_int2(e.x & ((1 << SRCB) - 1), e.y);
    }
}

// ---------------- fused gather + MLP ---------------------------------------
// Block = 4 waves, 64 nodes. Each wave owns 16 nodes.
// Gather: one node per 16-lane group (4 nodes in parallel per wave), 4 edges
// in flight per group, fp32 accum, +x, -> wave-private LDS tile.
// MLP: A-frags (bf16 hi/lo) from LDS, phase-1 h=relu(A@W1+b1) back to the
// tile, phase-2 out=h@W2+b2. No __syncthreads: tile is wave-private and LDS
// ops are in-order within a wave.
template<int H, bool RELU_OUT, bool OUT_BF16>
__global__ __launch_bounds__(256)
void k_fused(const ushort* __restrict__ in, void* __restrict__ outv,
             const int* __restrict__ rowptr, const int2* __restrict__ csr,
             const unsigned short* __restrict__ w1h, const unsigned short* __restrict__ w1l,
             const float* __restrict__ b1,
             const unsigned short* __restrict__ w2h, const unsigned short* __restrict__ w2l,
             const float* __restrict__ b2, int N) {
    constexpr int SH  = H + 4;      // LDS h-row stride
    constexpr int CG1 = H / 16;     // phase-1 col groups
    constexpr int KF2 = H / 32;     // phase-2 k frags
    __shared__ float hs[4 * 16 * SH];

    const int t = threadIdx.x;
    const int wv = t >> 6, lane = t & 63;
    const int m = lane & 15, q = lane >> 4;   // m: feature quad; q: node-in-batch / k-half
    const int node0 = blockIdx.x * 64 + wv * 16;
    float* hw = &hs[wv * 16 * SH];
    const ushort4* in4 = reinterpret_cast<const ushort4*>(in);

    // ---- preload rowptr boundaries for this wave's 16 nodes (one load) ----
    int rp_l = 0;
    {
        int idx = node0 + lane;
        if (lane <= 16) rp_l = rowptr[idx <= N ? idx : N];
    }

    // ---- hoist "+x" rows for all 4 batches ----
    ushort4 xr[4];
#pragma unroll
    for (int nb = 0; nb < 4; ++nb) {
        int node = node0 + nb * 4 + q;
        int nodeC = node < N ? node : N - 1;
        xr[nb] = in4[(size_t)nodeC * 16 + m];
    }

    // ---- gather: 4 nodes in parallel per wave, 4 edges in flight/group ----
#pragma unroll
    for (int nb = 0; nb < 4; ++nb) {
        const int nl  = nb * 4 + q;               // node-local 0..15
        const int beg = __shfl(rp_l, nl);
        const int end = __shfl(rp_l, nl + 1);
        float4 acc = make_float4(0.f, 0.f, 0.f, 0.f);
        for (int p = beg; p < end; p += 4) {
            int   s[4];
            float w[4];
#pragma unroll
            for (int u = 0; u < 4; ++u) {
                int i = p + u;
                int2 ev = make_int2(0, 0);
                if (i < end) ev = csr[i];         // 8B broadcast in group
                s[u] = ev.x;
                w[u] = __int_as_float(ev.y);      // 0.0f when inactive
            }
            ushort4 v4[4];
#pragma unroll
            for (int u = 0; u < 4; ++u)
                v4[u] = in4[(unsigned)s[u] * 16u + m];   // 4 rows in flight
#pragma unroll
            for (int u = 0; u < 4; ++u) {
                acc.x = fmaf(w[u], bf2f(v4[u].x), acc.x);
                acc.y = fmaf(w[u], bf2f(v4[u].y), acc.y);
                acc.z = fmaf(w[u], bf2f(v4[u].z), acc.z);
                acc.w = fmaf(w[u], bf2f(v4[u].w), acc.w);
            }
        }
        acc.x += bf2f(xr[nb].x); acc.y += bf2f(xr[nb].y);
        acc.z += bf2f(xr[nb].z); acc.w += bf2f(xr[nb].w);
        // all 64 lanes write: 4 rows at once, lane m writes its float4 quad
        *reinterpret_cast<float4*>(&hw[nl * SH + m * 4]) = acc;
    }

    // ---- A frags (K=64 -> 2 kf) from LDS, split hi/lo ----
    const bfrag* w1hp = reinterpret_cast<const bfrag*>(w1h);
    const bfrag* w1lp = reinterpret_cast<const bfrag*>(w1l);
    const bfrag* w2hp = reinterpret_cast<const bfrag*>(w2h);
    const bfrag* w2lp = reinterpret_cast<const bfrag*>(w2l);

    bfrag ah[2], al[2];
#pragma unroll
    for (int kf = 0; kf < 2; ++kf) {
        const float* base = &hw[m * SH + kf * 32 + q * 8];
        float4 u0 = *reinterpret_cast<const float4*>(base);
        float4 u1 = *reinterpret_cast<const float4*>(base + 4);
        float u[8] = {u0.x, u0.y, u0.z, u0.w, u1.x, u1.y, u1.z, u1.w};
#pragma unroll
        for (int j = 0; j < 8; ++j) {
            unsigned short hb = f2bf_rne(u[j]);
            ah[kf][j] = (short)hb;
            al[kf][j] = (short)f2bf_rne(u[j] - bf2f(hb));
        }
    }

    // ---- phase 1: h = relu(A@W1 + b1) -> LDS (wave-private tile) ----
#pragma unroll
    for (int cg = 0; cg < CG1; ++cg) {
        ffrag c = {0.f, 0.f, 0.f, 0.f};
#pragma unroll
        for (int kf = 0; kf < 2; ++kf) {
            bfrag bh = w1hp[(cg * 2 + kf) * 64 + lane];
            bfrag bl = w1lp[(cg * 2 + kf) * 64 + lane];
            c = __builtin_amdgcn_mfma_f32_16x16x32_bf16(ah[kf], bh, c, 0, 0, 0);
            c = __builtin_amdgcn_mfma_f32_16x16x32_bf16(al[kf], bh, c, 0, 0, 0);
            c = __builtin_amdgcn_mfma_f32_16x16x32_bf16(ah[kf], bl, c, 0, 0, 0);
        }
        float bias = b1[cg * 16 + m];
#pragma unroll
        for (int r = 0; r < 4; ++r) {
            float hv = fmaxf(c[r] + bias, 0.f);
            hw[(q * 4 + r) * SH + cg * 16 + m] = hv;   // row=node, col=h-col
        }
    }

    // ---- h -> A frags (hi/lo) ----
    bfrag gh[KF2], gl[KF2];
#pragma unroll
    for (int kf = 0; kf < KF2; ++kf) {
        const float* base = &hw[m * SH + kf * 32 + q * 8];
        float4 u0 = *reinterpret_cast<const float4*>(base);
        float4 u1 = *reinterpret_cast<const float4*>(base + 4);
        float u[8] = {u0.x, u0.y, u0.z, u0.w, u1.x, u1.y, u1.z, u1.w};
#pragma unroll
        for (int j = 0; j < 8; ++j) {
            unsigned short hb = f2bf_rne(u[j]);
            gh[kf][j] = (short)hb;
            gl[kf][j] = (short)f2bf_rne(u[j] - bf2f(hb));
        }
    }

    // ---- phase 2: out = h@W2 + b2 ----
#pragma unroll
    for (int cg = 0; cg < 4; ++cg) {
        ffrag c = {0.f, 0.f, 0.f, 0.f};
#pragma unroll
        for (int kf = 0; kf < KF2; ++kf) {
            bfrag bh = w2hp[(cg * KF2 + kf) * 64 + lane];
            bfrag bl = w2lp[(cg * KF2 + kf) * 64 + lane];
            c = __builtin_amdgcn_mfma_f32_16x16x32_bf16(gh[kf], bh, c, 0, 0, 0);
            c = __builtin_amdgcn_mfma_f32_16x16x32_bf16(gl[kf], bh, c, 0, 0, 0);
            c = __builtin_amdgcn_mfma_f32_16x16x32_bf16(gh[kf], bl, c, 0, 0, 0);
        }
        float bias = b2[cg * 16 + m];
#pragma unroll
        for (int r = 0; r < 4; ++r) {
            int nd = node0 + q * 4 + r;
            if (nd < N) {
                float v = c[r] + bias;
                if (RELU_OUT) v = fmaxf(v, 0.f);
                if (OUT_BF16)
                    ((unsigned short*)outv)[(size_t)nd * FEAT + cg * 16 + m] = f2bf_rne(v);
                else
                    ((float*)outv)[(size_t)nd * FEAT + cg * 16 + m] = v;
            }
        }
    }
}

// ---------------------------------------------------------------------------
extern "C" void kernel_launch(void* const* d_in, const int* in_sizes, int n_in,
                              void* d_out, int out_size, void* d_ws, size_t ws_size,
                              hipStream_t stream) {
    const float* x   = (const float*)d_in[0];
    const int*   ei  = (const int*)  d_in[1];
    const float* ew  = (const float*)d_in[2];
    const float* w11 = (const float*)d_in[3];
    const float* b11 = (const float*)d_in[4];
    const float* w12 = (const float*)d_in[5];
    const float* b12 = (const float*)d_in[6];
    const float* w21 = (const float*)d_in[7];
    const float* b21 = (const float*)d_in[8];
    const float* w22 = (const float*)d_in[9];
    const float* b22 = (const float*)d_in[10];
    const float* w31 = (const float*)d_in[11];
    const float* b31 = (const float*)d_in[12];
    const float* w32 = (const float*)d_in[13];
    const float* b32 = (const float*)d_in[14];

    const int N = in_sizes[0] / FEAT;   // 100000
    const int E = in_sizes[2];          // 1000000
    const int* srci = ei;
    const int* dsti = ei + E;
    const int NBINS = (N + BINW - 1) >> BSH;   // 782

    // ---- workspace layout ----
    unsigned short* xb0 = (unsigned short*)d_ws;             // [N*64] bf16
    unsigned short* xb1 = xb0 + (size_t)N * FEAT;            // [N*64] bf16
    int*   rowptr   = (int*)(xb1 + (size_t)N * FEAT);        // [N+1]
    int*   counts   = rowptr + (N + 1);                      // [NBINS*NBLK]
    int*   bintotal = counts + NBINS * NBLK;                 // [NBINS]
    int*   binstart = bintotal + NBINS;                      // [NBINS+1]
    size_t a16 = ((size_t)(binstart + NBINS + 1) + 15) & ~(size_t)15;
    int2*  binbuf   = (int2*)a16;                            // [E] (key, w)
    int2*  csr      = (int2*)(binbuf + E);                   // [E] (src, w)
    size_t pk = (size_t)(csr + E);
    unsigned short* p11h = (unsigned short*)pk;              // 4096 each for 64x64
    unsigned short* p11l = p11h + 4096;
    unsigned short* p12h = p11l + 4096;
    unsigned short* p12l = p12h + 4096;
    unsigned short* p21h = p12l + 4096;                      // 8192 for 64x128
    unsigned short* p21l = p21h + 8192;
    unsigned short* p22h = p21l + 8192;                      // 8192 for 128x64
    unsigned short* p22l = p22h + 8192;
    unsigned short* p31h = p22l + 8192;
    unsigned short* p31l = p31h + 4096;
    unsigned short* p32h = p31l + 4096;
    unsigned short* p32l = p32h + 4096;
    float* outF = (float*)d_out;                             // [N*64]

    const int n4   = N * 16;
    const int gCvt = (n4 + 255) / 256;
    const int gMlp = (N + 63) / 64;
    const int gPre = gCvt + NBLK + 128;

    // ---- pre: cvt + histogram + weight pack (one launch) ----
    k_pre<<<gPre, 256, 0, stream>>>((const float4*)x, (ushort4*)xb0, n4, gCvt,
                                    dsti, counts, E, NBINS,
                                    w11, w12, w21, w22, w31, w32,
                                    p11h, p11l, p12h, p12l, p21h, p21l,
                                    p22h, p22l, p31h, p31l, p32h, p32l);
    // ---- CSR build (scanB folded into place) ----
    k_scanA2 <<<NBINS, 256, 0, stream>>>(counts, bintotal, rowptr, NBINS, N, E);
    k_place2 <<<NBLK,  256, 0, stream>>>(srci, dsti, ew, counts, bintotal,
                                         binstart, binbuf, E, NBINS);
    k_binsort<<<NBINS, 256, 0, stream>>>(binbuf, binstart, rowptr, csr, N);

    // ---- fused layers (double-buffered activations) ----
    k_fused<64,  true,  true ><<<gMlp, 256, 0, stream>>>(xb0, xb1, rowptr, csr,
                                                         p11h, p11l, b11, p12h, p12l, b12, N);
    k_fused<128, true,  true ><<<gMlp, 256, 0, stream>>>(xb1, xb0, rowptr, csr,
                                                         p21h, p21l, b21, p22h, p22l, b22, N);
    k_fused<64,  false, false><<<gMlp, 256, 0, stream>>>(xb0, outF, rowptr, csr,
                                                         p31h, p31l, b31, p32h, p32l, b32, N);
}

// Round 4
// 290.918 us; speedup vs baseline: 1.2569x; 1.0994x over previous
//
#include <hip/hip_runtime.h>
#include <math.h>

// ---------------------------------------------------------------------------
// GIN, 3 layers, N=100000, E=1000000, D=64, fp32 in/out.
// Round 13: gather ILP attack. Round-12 post-mortem: still latency-bound
// (VALU 23%, MFMA 5%, HBM 13%) — only 4 row-loads in flight per node and a
// serial csr->row->FMA round trip every 4 edges (deg~10 -> 2.5 trips/node).
// Fix:
//   - p-loop step 16, fully unrolled: all 16 csr entries + all 16 row-loads
//     of a node issue before the FMA block waits (one memory round trip per
//     node in the common case).
//   - unconditional loads: csr[min(i,E-1)], weight zeroed for i>=end; no
//     per-edge exec-mask divergence.
//   VGPR ~52 -> ~95 (still <=128 needed for the LDS-limited 16 waves/CU).
// Everything else (CSR build, pre-kernel, MLP phases) unchanged from R12b.
// ---------------------------------------------------------------------------

#define FEAT  64
#define BINW  128          // nodes per bin
#define BSH   7            // log2(BINW)
#define NBLK  256          // edge-partition blocks
#define SRCB  25           // bits for src in packed key (N < 2^25)

typedef __attribute__((ext_vector_type(8))) short bfrag;   // 8 bf16 (4 VGPRs)
typedef __attribute__((ext_vector_type(4))) float ffrag;   // 4 fp32 acc

__device__ __forceinline__ unsigned short f2bf_rne(float x) {
    union { float f; unsigned u; } v; v.f = x;
    unsigned r = (v.u + 0x7fffu + ((v.u >> 16) & 1u)) >> 16;
    return (unsigned short)r;
}
__device__ __forceinline__ float bf2f(unsigned short h) {
    union { unsigned u; float f; } v; v.u = ((unsigned)h) << 16;
    return v.f;
}

// ---------------- weight pack helper ---------------------------------------
__device__ __forceinline__ void pack_one(const float* __restrict__ w,
                                         unsigned short* __restrict__ hi,
                                         unsigned short* __restrict__ lo,
                                         int K, int Hc, int i) {
    int KF = K >> 5;
    int j    = i & 7;
    int lane = (i >> 3) & 63;
    int fb   = i >> 9;
    int kf   = fb % KF;
    int cg   = fb / KF;
    int k    = kf * 32 + ((lane >> 4) << 3) + j;
    int col  = cg * 16 + (lane & 15);
    float x = w[k * Hc + col];
    unsigned short h = f2bf_rne(x);
    hi[i] = h;
    lo[i] = f2bf_rne(x - bf2f(h));
}

// ---------------- pre: cvt + cnt + pack, one launch ------------------------
__global__ __launch_bounds__(256)
void k_pre(const float4* __restrict__ x4, ushort4* __restrict__ xb4,
           int n4, int gCvt,
           const int* __restrict__ dst, int* __restrict__ counts,
           int E, int NBINS,
           const float* w11, const float* w12, const float* w21,
           const float* w22, const float* w31, const float* w32,
           unsigned short* p11h, unsigned short* p11l,
           unsigned short* p12h, unsigned short* p12l,
           unsigned short* p21h, unsigned short* p21l,
           unsigned short* p22h, unsigned short* p22l,
           unsigned short* p31h, unsigned short* p31l,
           unsigned short* p32h, unsigned short* p32l) {
    __shared__ int h[1024];
    const int bb = blockIdx.x, tid = threadIdx.x;
    if (bb < gCvt) {
        int i = bb * 256 + tid;
        if (i < n4) {
            float4 v = x4[i];
            ushort4 o;
            o.x = f2bf_rne(v.x); o.y = f2bf_rne(v.y);
            o.z = f2bf_rne(v.z); o.w = f2bf_rne(v.w);
            xb4[i] = o;
        }
    } else if (bb < gCvt + NBLK) {
        const int b = bb - gCvt;
        for (int i = tid; i < NBINS; i += 256) h[i] = 0;
        __syncthreads();
        const int chunk = (E + NBLK - 1) / NBLK;
        const int ebeg = b * chunk;
        const int eend = (ebeg + chunk < E) ? ebeg + chunk : E;
        for (int e = ebeg + tid; e < eend; e += 256)
            atomicAdd(&h[dst[e] >> BSH], 1);          // LDS atomic
        __syncthreads();
        for (int i = tid; i < NBINS; i += 256)
            counts[i * NBLK + b] = h[i];
    } else {
        int i = (bb - gCvt - NBLK) * 256 + tid;       // 0..32767
        if      (i <  4096) pack_one(w11, p11h, p11l,  64,  64, i);
        else if (i <  8192) pack_one(w12, p12h, p12l,  64,  64, i - 4096);
        else if (i < 16384) pack_one(w21, p21h, p21l,  64, 128, i - 8192);
        else if (i < 24576) pack_one(w22, p22h, p22l, 128,  64, i - 16384);
        else if (i < 28672) pack_one(w31, p31h, p31l,  64,  64, i - 24576);
        else                pack_one(w32, p32h, p32l,  64,  64, i - 28672);
    }
}

// ---------------- per-bin scan over the 256 partition blocks ---------------
__global__ __launch_bounds__(256)
void k_scanA2(int* __restrict__ counts, int* __restrict__ bintotal,
              int* __restrict__ rowptr, int NBINS, int N, int E) {
    __shared__ int tmp[256];
    const int bin = blockIdx.x, tid = threadIdx.x;
    int c = counts[bin * NBLK + tid];
    tmp[tid] = c;
    __syncthreads();
    for (int off = 1; off < 256; off <<= 1) {
        int t = (tid >= off) ? tmp[tid - off] : 0;
        __syncthreads();
        tmp[tid] += t;
        __syncthreads();
    }
    counts[bin * NBLK + tid] = tmp[tid] - c;      // exclusive within bin
    if (tid == 255) bintotal[bin] = tmp[255];
    if (bin == 0 && tid == 0) rowptr[N] = E;
}

// ---------------- place edges (local binstart scan, no scanB) --------------
__global__ __launch_bounds__(256)
void k_place2(const int* __restrict__ src, const int* __restrict__ dst,
              const float* __restrict__ ew, const int* __restrict__ counts,
              const int* __restrict__ bintotal, int* __restrict__ binstart,
              int2* __restrict__ binbuf, int E, int NBINS) {
    __shared__ int bs[1024];        // local exclusive prefix of bintotal
    __shared__ int tmp[256];
    __shared__ int base[1024];
    const int b = blockIdx.x, tid = threadIdx.x;

    int v[4]; int s = 0;
#pragma unroll
    for (int j = 0; j < 4; ++j) {
        int idx = tid * 4 + j;
        v[j] = (idx < NBINS) ? bintotal[idx] : 0;
        s += v[j];
    }
    tmp[tid] = s;
    __syncthreads();
    for (int off = 1; off < 256; off <<= 1) {
        int t = (tid >= off) ? tmp[tid - off] : 0;
        __syncthreads();
        tmp[tid] += t;
        __syncthreads();
    }
    int run = tmp[tid] - s;
#pragma unroll
    for (int j = 0; j < 4; ++j) {
        bs[tid * 4 + j] = run;
        run += v[j];
    }
    __syncthreads();

    if (b == 0) {
        for (int i = tid; i < NBINS; i += 256) binstart[i] = bs[i];
        if (tid == 0) binstart[NBINS] = E;
    }

    for (int i = tid; i < NBINS; i += 256)
        base[i] = bs[i] + counts[i * NBLK + b];
    __syncthreads();

    const int chunk = (E + NBLK - 1) / NBLK;
    const int ebeg = b * chunk;
    const int eend = (ebeg + chunk < E) ? ebeg + chunk : E;
    for (int e = ebeg + tid; e < eend; e += 256) {
        int d = dst[e];
        int slot = atomicAdd(&base[d >> BSH], 1);   // LDS atomic only
        int key = ((d & (BINW - 1)) << SRCB) | src[e];
        binbuf[slot] = make_int2(key, __float_as_int(ew[e]));
    }
}

// one block per bin: count 128 nodes -> scan -> rowptr -> place edges.
__global__ __launch_bounds__(256)
void k_binsort(const int2* __restrict__ binbuf, const int* __restrict__ binstart,
               int* __restrict__ rowptr, int2* __restrict__ csr, int N) {
    __shared__ int cnt[BINW];
    __shared__ int cur[BINW];
    const int b    = blockIdx.x;
    const int base = binstart[b];
    const int ne   = binstart[b + 1] - base;
    const int tid  = threadIdx.x;

    if (tid < BINW) cnt[tid] = 0;
    __syncthreads();
    for (int i = tid; i < ne; i += 256)
        atomicAdd(&cnt[(binbuf[base + i].x >> SRCB) & (BINW - 1)], 1);
    __syncthreads();
    if (tid < BINW) cur[tid] = cnt[tid];
    __syncthreads();
    for (int off = 1; off < BINW; off <<= 1) {
        int v = (tid < BINW && tid >= off) ? cur[tid - off] : 0;
        __syncthreads();
        if (tid < BINW) cur[tid] += v;
        __syncthreads();
    }
    if (tid < BINW) {
        int ex = cur[tid] - cnt[tid];
        int node = b * BINW + tid;
        if (node < N) rowptr[node] = base + ex;
        cur[tid] = ex;
    }
    __syncthreads();
    for (int i = tid; i < ne; i += 256) {
        int2 e = binbuf[base + i];
        int dl = (e.x >> SRCB) & (BINW - 1);
        int r = atomicAdd(&cur[dl], 1);
        csr[base + r] = make_int2(e.x & ((1 << SRCB) - 1), e.y);
    }
}

// ---------------- fused gather + MLP ---------------------------------------
// Block = 4 waves, 64 nodes. Each wave owns 16 nodes.
// Gather: one node per 16-lane group (4 nodes in parallel per wave), 16 edges
// in flight per group (step-16 unrolled, unconditional loads), fp32 accum,
// +x, -> wave-private LDS tile.
// MLP: A-frags (bf16 hi/lo) from LDS, phase-1 h=relu(A@W1+b1) back to the
// tile, phase-2 out=h@W2+b2. No __syncthreads: tile is wave-private and LDS
// ops are in-order within a wave.
template<int H, bool RELU_OUT, bool OUT_BF16>
__global__ __launch_bounds__(256)
void k_fused(const ushort* __restrict__ in, void* __restrict__ outv,
             const int* __restrict__ rowptr, const int2* __restrict__ csr,
             const unsigned short* __restrict__ w1h, const unsigned short* __restrict__ w1l,
             const float* __restrict__ b1,
             const unsigned short* __restrict__ w2h, const unsigned short* __restrict__ w2l,
             const float* __restrict__ b2, int N, int E) {
    constexpr int SH  = H + 4;      // LDS h-row stride
    constexpr int CG1 = H / 16;     // phase-1 col groups
    constexpr int KF2 = H / 32;     // phase-2 k frags
    __shared__ float hs[4 * 16 * SH];

    const int t = threadIdx.x;
    const int wv = t >> 6, lane = t & 63;
    const int m = lane & 15, q = lane >> 4;   // m: feature quad; q: node-in-batch / k-half
    const int node0 = blockIdx.x * 64 + wv * 16;
    float* hw = &hs[wv * 16 * SH];
    const ushort4* in4 = reinterpret_cast<const ushort4*>(in);

    // ---- preload rowptr boundaries for this wave's 16 nodes (one load) ----
    int rp_l = 0;
    {
        int idx = node0 + lane;
        if (lane <= 16) rp_l = rowptr[idx <= N ? idx : N];
    }

    // ---- hoist "+x" rows for all 4 batches ----
    ushort4 xr[4];
#pragma unroll
    for (int nb = 0; nb < 4; ++nb) {
        int node = node0 + nb * 4 + q;
        int nodeC = node < N ? node : N - 1;
        xr[nb] = in4[(size_t)nodeC * 16 + m];
    }

    // ---- gather: 4 nodes in parallel per wave, 16 edges in flight/group ----
#pragma unroll
    for (int nb = 0; nb < 4; ++nb) {
        const int nl  = nb * 4 + q;               // node-local 0..15
        const int beg = __shfl(rp_l, nl);
        const int end = __shfl(rp_l, nl + 1);
        float4 acc = make_float4(0.f, 0.f, 0.f, 0.f);
        for (int p = beg; p < end; p += 16) {
            int   s[16];
            float w[16];
#pragma unroll
            for (int u = 0; u < 16; ++u) {
                int i = p + u;
                int2 ev = csr[i < E ? i : E - 1];   // always issued
                s[u] = ev.x;
                w[u] = (i < end) ? __int_as_float(ev.y) : 0.f;
            }
            ushort4 v4[16];
#pragma unroll
            for (int u = 0; u < 16; ++u)
                v4[u] = in4[(unsigned)s[u] * 16u + m];   // 16 rows in flight
#pragma unroll
            for (int u = 0; u < 16; ++u) {
                acc.x = fmaf(w[u], bf2f(v4[u].x), acc.x);
                acc.y = fmaf(w[u], bf2f(v4[u].y), acc.y);
                acc.z = fmaf(w[u], bf2f(v4[u].z), acc.z);
                acc.w = fmaf(w[u], bf2f(v4[u].w), acc.w);
            }
        }
        acc.x += bf2f(xr[nb].x); acc.y += bf2f(xr[nb].y);
        acc.z += bf2f(xr[nb].z); acc.w += bf2f(xr[nb].w);
        // all 64 lanes write: 4 rows at once, lane m writes its float4 quad
        *reinterpret_cast<float4*>(&hw[nl * SH + m * 4]) = acc;
    }

    // ---- A frags (K=64 -> 2 kf) from LDS, split hi/lo ----
    const bfrag* w1hp = reinterpret_cast<const bfrag*>(w1h);
    const bfrag* w1lp = reinterpret_cast<const bfrag*>(w1l);
    const bfrag* w2hp = reinterpret_cast<const bfrag*>(w2h);
    const bfrag* w2lp = reinterpret_cast<const bfrag*>(w2l);

    bfrag ah[2], al[2];
#pragma unroll
    for (int kf = 0; kf < 2; ++kf) {
        const float* base = &hw[m * SH + kf * 32 + q * 8];
        float4 u0 = *reinterpret_cast<const float4*>(base);
        float4 u1 = *reinterpret_cast<const float4*>(base + 4);
        float u[8] = {u0.x, u0.y, u0.z, u0.w, u1.x, u1.y, u1.z, u1.w};
#pragma unroll
        for (int j = 0; j < 8; ++j) {
            unsigned short hb = f2bf_rne(u[j]);
            ah[kf][j] = (short)hb;
            al[kf][j] = (short)f2bf_rne(u[j] - bf2f(hb));
        }
    }

    // ---- phase 1: h = relu(A@W1 + b1) -> LDS (wave-private tile) ----
#pragma unroll
    for (int cg = 0; cg < CG1; ++cg) {
        ffrag c = {0.f, 0.f, 0.f, 0.f};
#pragma unroll
        for (int kf = 0; kf < 2; ++kf) {
            bfrag bh = w1hp[(cg * 2 + kf) * 64 + lane];
            bfrag bl = w1lp[(cg * 2 + kf) * 64 + lane];
            c = __builtin_amdgcn_mfma_f32_16x16x32_bf16(ah[kf], bh, c, 0, 0, 0);
            c = __builtin_amdgcn_mfma_f32_16x16x32_bf16(al[kf], bh, c, 0, 0, 0);
            c = __builtin_amdgcn_mfma_f32_16x16x32_bf16(ah[kf], bl, c, 0, 0, 0);
        }
        float bias = b1[cg * 16 + m];
#pragma unroll
        for (int r = 0; r < 4; ++r) {
            float hv = fmaxf(c[r] + bias, 0.f);
            hw[(q * 4 + r) * SH + cg * 16 + m] = hv;   // row=node, col=h-col
        }
    }

    // ---- h -> A frags (hi/lo) ----
    bfrag gh[KF2], gl[KF2];
#pragma unroll
    for (int kf = 0; kf < KF2; ++kf) {
        const float* base = &hw[m * SH + kf * 32 + q * 8];
        float4 u0 = *reinterpret_cast<const float4*>(base);
        float4 u1 = *reinterpret_cast<const float4*>(base + 4);
        float u[8] = {u0.x, u0.y, u0.z, u0.w, u1.x, u1.y, u1.z, u1.w};
#pragma unroll
        for (int j = 0; j < 8; ++j) {
            unsigned short hb = f2bf_rne(u[j]);
            gh[kf][j] = (short)hb;
            gl[kf][j] = (short)f2bf_rne(u[j] - bf2f(hb));
        }
    }

    // ---- phase 2: out = h@W2 + b2 ----
#pragma unroll
    for (int cg = 0; cg < 4; ++cg) {
        ffrag c = {0.f, 0.f, 0.f, 0.f};
#pragma unroll
        for (int kf = 0; kf < KF2; ++kf) {
            bfrag bh = w2hp[(cg * KF2 + kf) * 64 + lane];
            bfrag bl = w2lp[(cg * KF2 + kf) * 64 + lane];
            c = __builtin_amdgcn_mfma_f32_16x16x32_bf16(gh[kf], bh, c, 0, 0, 0);
            c = __builtin_amdgcn_mfma_f32_16x16x32_bf16(gl[kf], bh, c, 0, 0, 0);
            c = __builtin_amdgcn_mfma_f32_16x16x32_bf16(gh[kf], bl, c, 0, 0, 0);
        }
        float bias = b2[cg * 16 + m];
#pragma unroll
        for (int r = 0; r < 4; ++r) {
            int nd = node0 + q * 4 + r;
            if (nd < N) {
                float v = c[r] + bias;
                if (RELU_OUT) v = fmaxf(v, 0.f);
                if (OUT_BF16)
                    ((unsigned short*)outv)[(size_t)nd * FEAT + cg * 16 + m] = f2bf_rne(v);
                else
                    ((float*)outv)[(size_t)nd * FEAT + cg * 16 + m] = v;
            }
        }
    }
}

// ---------------------------------------------------------------------------
extern "C" void kernel_launch(void* const* d_in, const int* in_sizes, int n_in,
                              void* d_out, int out_size, void* d_ws, size_t ws_size,
                              hipStream_t stream) {
    const float* x   = (const float*)d_in[0];
    const int*   ei  = (const int*)  d_in[1];
    const float* ew  = (const float*)d_in[2];
    const float* w11 = (const float*)d_in[3];
    const float* b11 = (const float*)d_in[4];
    const float* w12 = (const float*)d_in[5];
    const float* b12 = (const float*)d_in[6];
    const float* w21 = (const float*)d_in[7];
    const float* b21 = (const float*)d_in[8];
    const float* w22 = (const float*)d_in[9];
    const float* b22 = (const float*)d_in[10];
    const float* w31 = (const float*)d_in[11];
    const float* b31 = (const float*)d_in[12];
    const float* w32 = (const float*)d_in[13];
    const float* b32 = (const float*)d_in[14];

    const int N = in_sizes[0] / FEAT;   // 100000
    const int E = in_sizes[2];          // 1000000
    const int* srci = ei;
    const int* dsti = ei + E;
    const int NBINS = (N + BINW - 1) >> BSH;   // 782

    // ---- workspace layout ----
    unsigned short* xb0 = (unsigned short*)d_ws;             // [N*64] bf16
    unsigned short* xb1 = xb0 + (size_t)N * FEAT;            // [N*64] bf16
    int*   rowptr   = (int*)(xb1 + (size_t)N * FEAT);        // [N+1]
    int*   counts   = rowptr + (N + 1);                      // [NBINS*NBLK]
    int*   bintotal = counts + NBINS * NBLK;                 // [NBINS]
    int*   binstart = bintotal + NBINS;                      // [NBINS+1]
    size_t a16 = ((size_t)(binstart + NBINS + 1) + 15) & ~(size_t)15;
    int2*  binbuf   = (int2*)a16;                            // [E] (key, w)
    int2*  csr      = (int2*)(binbuf + E);                   // [E] (src, w)
    size_t pk = (size_t)(csr + E);
    unsigned short* p11h = (unsigned short*)pk;              // 4096 each for 64x64
    unsigned short* p11l = p11h + 4096;
    unsigned short* p12h = p11l + 4096;
    unsigned short* p12l = p12h + 4096;
    unsigned short* p21h = p12l + 4096;                      // 8192 for 64x128
    unsigned short* p21l = p21h + 8192;
    unsigned short* p22h = p21l + 8192;                      // 8192 for 128x64
    unsigned short* p22l = p22h + 8192;
    unsigned short* p31h = p22l + 8192;
    unsigned short* p31l = p31h + 4096;
    unsigned short* p32h = p31l + 4096;
    unsigned short* p32l = p32h + 4096;
    float* outF = (float*)d_out;                             // [N*64]

    const int n4   = N * 16;
    const int gCvt = (n4 + 255) / 256;
    const int gMlp = (N + 63) / 64;
    const int gPre = gCvt + NBLK + 128;

    // ---- pre: cvt + histogram + weight pack (one launch) ----
    k_pre<<<gPre, 256, 0, stream>>>((const float4*)x, (ushort4*)xb0, n4, gCvt,
                                    dsti, counts, E, NBINS,
                                    w11, w12, w21, w22, w31, w32,
                                    p11h, p11l, p12h, p12l, p21h, p21l,
                                    p22h, p22l, p31h, p31l, p32h, p32l);
    // ---- CSR build (scanB folded into place) ----
    k_scanA2 <<<NBINS, 256, 0, stream>>>(counts, bintotal, rowptr, NBINS, N, E);
    k_place2 <<<NBLK,  256, 0, stream>>>(srci, dsti, ew, counts, bintotal,
                                         binstart, binbuf, E, NBINS);
    k_binsort<<<NBINS, 256, 0, stream>>>(binbuf, binstart, rowptr, csr, N);

    // ---- fused layers (double-buffered activations) ----
    k_fused<64,  true,  true ><<<gMlp, 256, 0, stream>>>(xb0, xb1, rowptr, csr,
                                                         p11h, p11l, b11, p12h, p12l, b12, N, E);
    k_fused<128, true,  true ><<<gMlp, 256, 0, stream>>>(xb1, xb0, rowptr, csr,
                                                         p21h, p21l, b21, p22h, p22l, b22, N, E);
    k_fused<64,  false, false><<<gMlp, 256, 0, stream>>>(xb0, outF, rowptr, csr,
                                                         p31h, p31l, b31, p32h, p32l, b32, N, E);
}

// Round 5
// 278.230 us; speedup vs baseline: 1.3142x; 1.0456x over previous
//
#include <hip/hip_runtime.h>
#include <math.h>

// ---------------------------------------------------------------------------
// GIN, 3 layers, N=100000, E=1000000, D=64, fp32 in/out.
// Round 14: wave-count attack. R13 post-mortem: still latency-bound (VALU
// 30%, MFMA 6%, HBM 16%, Occ 30%) and the GRID (6250 waves) was smaller than
// chip residency (8192) with LDS capping 16 waves/CU on the H=128 layer.
// Fix: 2-wave tile cooperation.
//   - block = 4 waves = 32 nodes: two 16-node MFMA tiles, 2 waves per tile.
//   - each wave gathers 8 nodes (2 serial batches of 4-parallel, 16 edges in
//     flight per group, unchanged inner loop).
//   - MLP split: phase-1 col-groups split between the tile's 2 waves;
//     phase-2 output col-groups split; each wave does full A/h frag prep.
//   - 3 block barriers (gather->Aread, Aread->hwrite [h overwrites input
//     tile], hwrite->phase2 read).
//   - LDS/block: H=128 16.9KB (was 33.8) -> 8 blocks/CU = 32 waves/CU;
//     grid = 3125 blocks = 12500 waves (2x), N%32==0 so no tail tiles.
// CSR build + pre kernel unchanged from R13.
// ---------------------------------------------------------------------------

#define FEAT  64
#define BINW  128          // nodes per bin
#define BSH   7            // log2(BINW)
#define NBLK  256          // edge-partition blocks
#define SRCB  25           // bits for src in packed key (N < 2^25)

typedef __attribute__((ext_vector_type(8))) short bfrag;   // 8 bf16 (4 VGPRs)
typedef __attribute__((ext_vector_type(4))) float ffrag;   // 4 fp32 acc

__device__ __forceinline__ unsigned short f2bf_rne(float x) {
    union { float f; unsigned u; } v; v.f = x;
    unsigned r = (v.u + 0x7fffu + ((v.u >> 16) & 1u)) >> 16;
    return (unsigned short)r;
}
__device__ __forceinline__ float bf2f(unsigned short h) {
    union { unsigned u; float f; } v; v.u = ((unsigned)h) << 16;
    return v.f;
}

// ---------------- weight pack helper ---------------------------------------
__device__ __forceinline__ void pack_one(const float* __restrict__ w,
                                         unsigned short* __restrict__ hi,
                                         unsigned short* __restrict__ lo,
                                         int K, int Hc, int i) {
    int KF = K >> 5;
    int j    = i & 7;
    int lane = (i >> 3) & 63;
    int fb   = i >> 9;
    int kf   = fb % KF;
    int cg   = fb / KF;
    int k    = kf * 32 + ((lane >> 4) << 3) + j;
    int col  = cg * 16 + (lane & 15);
    float x = w[k * Hc + col];
    unsigned short h = f2bf_rne(x);
    hi[i] = h;
    lo[i] = f2bf_rne(x - bf2f(h));
}

// ---------------- pre: cvt + cnt + pack, one launch ------------------------
__global__ __launch_bounds__(256)
void k_pre(const float4* __restrict__ x4, ushort4* __restrict__ xb4,
           int n4, int gCvt,
           const int* __restrict__ dst, int* __restrict__ counts,
           int E, int NBINS,
           const float* w11, const float* w12, const float* w21,
           const float* w22, const float* w31, const float* w32,
           unsigned short* p11h, unsigned short* p11l,
           unsigned short* p12h, unsigned short* p12l,
           unsigned short* p21h, unsigned short* p21l,
           unsigned short* p22h, unsigned short* p22l,
           unsigned short* p31h, unsigned short* p31l,
           unsigned short* p32h, unsigned short* p32l) {
    __shared__ int h[1024];
    const int bb = blockIdx.x, tid = threadIdx.x;
    if (bb < gCvt) {
        int i = bb * 256 + tid;
        if (i < n4) {
            float4 v = x4[i];
            ushort4 o;
            o.x = f2bf_rne(v.x); o.y = f2bf_rne(v.y);
            o.z = f2bf_rne(v.z); o.w = f2bf_rne(v.w);
            xb4[i] = o;
        }
    } else if (bb < gCvt + NBLK) {
        const int b = bb - gCvt;
        for (int i = tid; i < NBINS; i += 256) h[i] = 0;
        __syncthreads();
        const int chunk = (E + NBLK - 1) / NBLK;
        const int ebeg = b * chunk;
        const int eend = (ebeg + chunk < E) ? ebeg + chunk : E;
        for (int e = ebeg + tid; e < eend; e += 256)
            atomicAdd(&h[dst[e] >> BSH], 1);          // LDS atomic
        __syncthreads();
        for (int i = tid; i < NBINS; i += 256)
            counts[i * NBLK + b] = h[i];
    } else {
        int i = (bb - gCvt - NBLK) * 256 + tid;       // 0..32767
        if      (i <  4096) pack_one(w11, p11h, p11l,  64,  64, i);
        else if (i <  8192) pack_one(w12, p12h, p12l,  64,  64, i - 4096);
        else if (i < 16384) pack_one(w21, p21h, p21l,  64, 128, i - 8192);
        else if (i < 24576) pack_one(w22, p22h, p22l, 128,  64, i - 16384);
        else if (i < 28672) pack_one(w31, p31h, p31l,  64,  64, i - 24576);
        else                pack_one(w32, p32h, p32l,  64,  64, i - 28672);
    }
}

// ---------------- per-bin scan over the 256 partition blocks ---------------
__global__ __launch_bounds__(256)
void k_scanA2(int* __restrict__ counts, int* __restrict__ bintotal,
              int* __restrict__ rowptr, int NBINS, int N, int E) {
    __shared__ int tmp[256];
    const int bin = blockIdx.x, tid = threadIdx.x;
    int c = counts[bin * NBLK + tid];
    tmp[tid] = c;
    __syncthreads();
    for (int off = 1; off < 256; off <<= 1) {
        int t = (tid >= off) ? tmp[tid - off] : 0;
        __syncthreads();
        tmp[tid] += t;
        __syncthreads();
    }
    counts[bin * NBLK + tid] = tmp[tid] - c;      // exclusive within bin
    if (tid == 255) bintotal[bin] = tmp[255];
    if (bin == 0 && tid == 0) rowptr[N] = E;
}

// ---------------- place edges (local binstart scan, no scanB) --------------
__global__ __launch_bounds__(256)
void k_place2(const int* __restrict__ src, const int* __restrict__ dst,
              const float* __restrict__ ew, const int* __restrict__ counts,
              const int* __restrict__ bintotal, int* __restrict__ binstart,
              int2* __restrict__ binbuf, int E, int NBINS) {
    __shared__ int bs[1024];        // local exclusive prefix of bintotal
    __shared__ int tmp[256];
    __shared__ int base[1024];
    const int b = blockIdx.x, tid = threadIdx.x;

    int v[4]; int s = 0;
#pragma unroll
    for (int j = 0; j < 4; ++j) {
        int idx = tid * 4 + j;
        v[j] = (idx < NBINS) ? bintotal[idx] : 0;
        s += v[j];
    }
    tmp[tid] = s;
    __syncthreads();
    for (int off = 1; off < 256; off <<= 1) {
        int t = (tid >= off) ? tmp[tid - off] : 0;
        __syncthreads();
        tmp[tid] += t;
        __syncthreads();
    }
    int run = tmp[tid] - s;
#pragma unroll
    for (int j = 0; j < 4; ++j) {
        bs[tid * 4 + j] = run;
        run += v[j];
    }
    __syncthreads();

    if (b == 0) {
        for (int i = tid; i < NBINS; i += 256) binstart[i] = bs[i];
        if (tid == 0) binstart[NBINS] = E;
    }

    for (int i = tid; i < NBINS; i += 256)
        base[i] = bs[i] + counts[i * NBLK + b];
    __syncthreads();

    const int chunk = (E + NBLK - 1) / NBLK;
    const int ebeg = b * chunk;
    const int eend = (ebeg + chunk < E) ? ebeg + chunk : E;
    for (int e = ebeg + tid; e < eend; e += 256) {
        int d = dst[e];
        int slot = atomicAdd(&base[d >> BSH], 1);   // LDS atomic only
        int key = ((d & (BINW - 1)) << SRCB) | src[e];
        binbuf[slot] = make_int2(key, __float_as_int(ew[e]));
    }
}

// one block per bin: count 128 nodes -> scan -> rowptr -> place edges.
__global__ __launch_bounds__(256)
void k_binsort(const int2* __restrict__ binbuf, const int* __restrict__ binstart,
               int* __restrict__ rowptr, int2* __restrict__ csr, int N) {
    __shared__ int cnt[BINW];
    __shared__ int cur[BINW];
    const int b    = blockIdx.x;
    const int base = binstart[b];
    const int ne   = binstart[b + 1] - base;
    const int tid  = threadIdx.x;

    if (tid < BINW) cnt[tid] = 0;
    __syncthreads();
    for (int i = tid; i < ne; i += 256)
        atomicAdd(&cnt[(binbuf[base + i].x >> SRCB) & (BINW - 1)], 1);
    __syncthreads();
    if (tid < BINW) cur[tid] = cnt[tid];
    __syncthreads();
    for (int off = 1; off < BINW; off <<= 1) {
        int v = (tid < BINW && tid >= off) ? cur[tid - off] : 0;
        __syncthreads();
        if (tid < BINW) cur[tid] += v;
        __syncthreads();
    }
    if (tid < BINW) {
        int ex = cur[tid] - cnt[tid];
        int node = b * BINW + tid;
        if (node < N) rowptr[node] = base + ex;
        cur[tid] = ex;
    }
    __syncthreads();
    for (int i = tid; i < ne; i += 256) {
        int2 e = binbuf[base + i];
        int dl = (e.x >> SRCB) & (BINW - 1);
        int r = atomicAdd(&cur[dl], 1);
        csr[base + r] = make_int2(e.x & ((1 << SRCB) - 1), e.y);
    }
}

// ---------------- fused gather + MLP (2-wave tile cooperation) -------------
// Block = 4 waves = 32 nodes: two 16-node tiles, 2 waves per tile.
// Gather: each wave owns 8 nodes of its tile (2 batches x 4-parallel nodes,
// 16 edges in flight per 16-lane group, unconditional loads).
// MLP: the tile's 2 waves split phase-1 col-groups and phase-2 output
// col-groups; each wave does full frag prep from the shared tile LDS.
template<int H, bool RELU_OUT, bool OUT_BF16>
__global__ __launch_bounds__(256)
void k_fused(const ushort* __restrict__ in, void* __restrict__ outv,
             const int* __restrict__ rowptr, const int2* __restrict__ csr,
             const unsigned short* __restrict__ w1h, const unsigned short* __restrict__ w1l,
             const float* __restrict__ b1,
             const unsigned short* __restrict__ w2h, const unsigned short* __restrict__ w2l,
             const float* __restrict__ b2, int N, int E) {
    constexpr int SH  = H + 4;      // LDS h-row stride
    constexpr int CG1 = H / 16;     // phase-1 col groups (split across 2 waves)
    constexpr int CGH = CG1 / 2;    // per-wave phase-1 col groups
    constexpr int KF2 = H / 32;     // phase-2 k frags
    __shared__ float hs[2 * 16 * SH];   // two 16-node tiles

    const int t = threadIdx.x;
    const int wv = t >> 6, lane = t & 63;
    const int tile = wv >> 1, wk = wv & 1;    // tile 0/1, wave-in-tile 0/1
    const int m = lane & 15, q = lane >> 4;
    const int tnode0 = blockIdx.x * 32 + tile * 16;   // tile's first node
    float* hw = &hs[tile * 16 * SH];
    const ushort4* in4 = reinterpret_cast<const ushort4*>(in);

    // ---- preload rowptr boundaries for this wave's 8 nodes (one load) ----
    int rp_l = 0;
    {
        int idx = tnode0 + wk * 8 + lane;
        if (lane <= 8) rp_l = rowptr[idx <= N ? idx : N];
    }

    // ---- hoist "+x" rows for both batches ----
    ushort4 xr[2];
#pragma unroll
    for (int nb = 0; nb < 2; ++nb) {
        int node = tnode0 + wk * 8 + nb * 4 + q;
        int nodeC = node < N ? node : N - 1;
        xr[nb] = in4[(size_t)nodeC * 16 + m];
    }

    // ---- gather: 4 nodes in parallel per wave, 16 edges in flight/group ----
#pragma unroll
    for (int nb = 0; nb < 2; ++nb) {
        const int nl8 = nb * 4 + q;               // 0..7 within wave's nodes
        const int nl  = wk * 8 + nl8;             // row within tile 0..15
        const int beg = __shfl(rp_l, nl8);
        const int end = __shfl(rp_l, nl8 + 1);
        float4 acc = make_float4(0.f, 0.f, 0.f, 0.f);
        for (int p = beg; p < end; p += 16) {
            int   s[16];
            float w[16];
#pragma unroll
            for (int u = 0; u < 16; ++u) {
                int i = p + u;
                int2 ev = csr[i < E ? i : E - 1];   // always issued
                s[u] = ev.x;
                w[u] = (i < end) ? __int_as_float(ev.y) : 0.f;
            }
            ushort4 v4[16];
#pragma unroll
            for (int u = 0; u < 16; ++u)
                v4[u] = in4[(unsigned)s[u] * 16u + m];   // 16 rows in flight
#pragma unroll
            for (int u = 0; u < 16; ++u) {
                acc.x = fmaf(w[u], bf2f(v4[u].x), acc.x);
                acc.y = fmaf(w[u], bf2f(v4[u].y), acc.y);
                acc.z = fmaf(w[u], bf2f(v4[u].z), acc.z);
                acc.w = fmaf(w[u], bf2f(v4[u].w), acc.w);
            }
        }
        acc.x += bf2f(xr[nb].x); acc.y += bf2f(xr[nb].y);
        acc.z += bf2f(xr[nb].z); acc.w += bf2f(xr[nb].w);
        *reinterpret_cast<float4*>(&hw[nl * SH + m * 4]) = acc;
    }
    __syncthreads();   // tile rows complete (both waves)

    // ---- A frags (K=64 -> 2 kf) from shared tile, split hi/lo ----
    const bfrag* w1hp = reinterpret_cast<const bfrag*>(w1h);
    const bfrag* w1lp = reinterpret_cast<const bfrag*>(w1l);
    const bfrag* w2hp = reinterpret_cast<const bfrag*>(w2h);
    const bfrag* w2lp = reinterpret_cast<const bfrag*>(w2l);

    bfrag ah[2], al[2];
#pragma unroll
    for (int kf = 0; kf < 2; ++kf) {
        const float* base = &hw[m * SH + kf * 32 + q * 8];
        float4 u0 = *reinterpret_cast<const float4*>(base);
        float4 u1 = *reinterpret_cast<const float4*>(base + 4);
        float u[8] = {u0.x, u0.y, u0.z, u0.w, u1.x, u1.y, u1.z, u1.w};
#pragma unroll
        for (int j = 0; j < 8; ++j) {
            unsigned short hb = f2bf_rne(u[j]);
            ah[kf][j] = (short)hb;
            al[kf][j] = (short)f2bf_rne(u[j] - bf2f(hb));
        }
    }
    __syncthreads();   // all A-frags read before h overwrites the tile

    // ---- phase 1: h = relu(A@W1 + b1) -> LDS (cg split across 2 waves) ----
#pragma unroll
    for (int cgi = 0; cgi < CGH; ++cgi) {
        const int cg = wk * CGH + cgi;
        ffrag c = {0.f, 0.f, 0.f, 0.f};
#pragma unroll
        for (int kf = 0; kf < 2; ++kf) {
            bfrag bh = w1hp[(cg * 2 + kf) * 64 + lane];
            bfrag bl = w1lp[(cg * 2 + kf) * 64 + lane];
            c = __builtin_amdgcn_mfma_f32_16x16x32_bf16(ah[kf], bh, c, 0, 0, 0);
            c = __builtin_amdgcn_mfma_f32_16x16x32_bf16(al[kf], bh, c, 0, 0, 0);
            c = __builtin_amdgcn_mfma_f32_16x16x32_bf16(ah[kf], bl, c, 0, 0, 0);
        }
        float bias = b1[cg * 16 + m];
#pragma unroll
        for (int r = 0; r < 4; ++r) {
            float hv = fmaxf(c[r] + bias, 0.f);
            hw[(q * 4 + r) * SH + cg * 16 + m] = hv;   // row=node, col=h-col
        }
    }
    __syncthreads();   // h complete (both waves)

    // ---- h -> A frags (hi/lo), full K per wave ----
    bfrag gh[KF2], gl[KF2];
#pragma unroll
    for (int kf = 0; kf < KF2; ++kf) {
        const float* base = &hw[m * SH + kf * 32 + q * 8];
        float4 u0 = *reinterpret_cast<const float4*>(base);
        float4 u1 = *reinterpret_cast<const float4*>(base + 4);
        float u[8] = {u0.x, u0.y, u0.z, u0.w, u1.x, u1.y, u1.z, u1.w};
#pragma unroll
        for (int j = 0; j < 8; ++j) {
            unsigned short hb = f2bf_rne(u[j]);
            gh[kf][j] = (short)hb;
            gl[kf][j] = (short)f2bf_rne(u[j] - bf2f(hb));
        }
    }

    // ---- phase 2: out = h@W2 + b2 (output cg split across 2 waves) ----
#pragma unroll
    for (int cgi = 0; cgi < 2; ++cgi) {
        const int cg = wk * 2 + cgi;
        ffrag c = {0.f, 0.f, 0.f, 0.f};
#pragma unroll
        for (int kf = 0; kf < KF2; ++kf) {
            bfrag bh = w2hp[(cg * KF2 + kf) * 64 + lane];
            bfrag bl = w2lp[(cg * KF2 + kf) * 64 + lane];
            c = __builtin_amdgcn_mfma_f32_16x16x32_bf16(gh[kf], bh, c, 0, 0, 0);
            c = __builtin_amdgcn_mfma_f32_16x16x32_bf16(gl[kf], bh, c, 0, 0, 0);
            c = __builtin_amdgcn_mfma_f32_16x16x32_bf16(gh[kf], bl, c, 0, 0, 0);
        }
        float bias = b2[cg * 16 + m];
#pragma unroll
        for (int r = 0; r < 4; ++r) {
            int nd = tnode0 + q * 4 + r;
            if (nd < N) {
                float v = c[r] + bias;
                if (RELU_OUT) v = fmaxf(v, 0.f);
                if (OUT_BF16)
                    ((unsigned short*)outv)[(size_t)nd * FEAT + cg * 16 + m] = f2bf_rne(v);
                else
                    ((float*)outv)[(size_t)nd * FEAT + cg * 16 + m] = v;
            }
        }
    }
}

// ---------------------------------------------------------------------------
extern "C" void kernel_launch(void* const* d_in, const int* in_sizes, int n_in,
                              void* d_out, int out_size, void* d_ws, size_t ws_size,
                              hipStream_t stream) {
    const float* x   = (const float*)d_in[0];
    const int*   ei  = (const int*)  d_in[1];
    const float* ew  = (const float*)d_in[2];
    const float* w11 = (const float*)d_in[3];
    const float* b11 = (const float*)d_in[4];
    const float* w12 = (const float*)d_in[5];
    const float* b12 = (const float*)d_in[6];
    const float* w21 = (const float*)d_in[7];
    const float* b21 = (const float*)d_in[8];
    const float* w22 = (const float*)d_in[9];
    const float* b22 = (const float*)d_in[10];
    const float* w31 = (const float*)d_in[11];
    const float* b31 = (const float*)d_in[12];
    const float* w32 = (const float*)d_in[13];
    const float* b32 = (const float*)d_in[14];

    const int N = in_sizes[0] / FEAT;   // 100000
    const int E = in_sizes[2];          // 1000000
    const int* srci = ei;
    const int* dsti = ei + E;
    const int NBINS = (N + BINW - 1) >> BSH;   // 782

    // ---- workspace layout ----
    unsigned short* xb0 = (unsigned short*)d_ws;             // [N*64] bf16
    unsigned short* xb1 = xb0 + (size_t)N * FEAT;            // [N*64] bf16
    int*   rowptr   = (int*)(xb1 + (size_t)N * FEAT);        // [N+1]
    int*   counts   = rowptr + (N + 1);                      // [NBINS*NBLK]
    int*   bintotal = counts + NBINS * NBLK;                 // [NBINS]
    int*   binstart = bintotal + NBINS;                      // [NBINS+1]
    size_t a16 = ((size_t)(binstart + NBINS + 1) + 15) & ~(size_t)15;
    int2*  binbuf   = (int2*)a16;                            // [E] (key, w)
    int2*  csr      = (int2*)(binbuf + E);                   // [E] (src, w)
    size_t pk = (size_t)(csr + E);
    unsigned short* p11h = (unsigned short*)pk;              // 4096 each for 64x64
    unsigned short* p11l = p11h + 4096;
    unsigned short* p12h = p11l + 4096;
    unsigned short* p12l = p12h + 4096;
    unsigned short* p21h = p12l + 4096;                      // 8192 for 64x128
    unsigned short* p21l = p21h + 8192;
    unsigned short* p22h = p21l + 8192;                      // 8192 for 128x64
    unsigned short* p22l = p22h + 8192;
    unsigned short* p31h = p22l + 8192;
    unsigned short* p31l = p31h + 4096;
    unsigned short* p32h = p31l + 4096;
    unsigned short* p32l = p32h + 4096;
    float* outF = (float*)d_out;                             // [N*64]

    const int n4   = N * 16;
    const int gCvt = (n4 + 255) / 256;
    const int gMlp = (N + 31) / 32;            // 3125 blocks, 12500 waves
    const int gPre = gCvt + NBLK + 128;

    // ---- pre: cvt + histogram + weight pack (one launch) ----
    k_pre<<<gPre, 256, 0, stream>>>((const float4*)x, (ushort4*)xb0, n4, gCvt,
                                    dsti, counts, E, NBINS,
                                    w11, w12, w21, w22, w31, w32,
                                    p11h, p11l, p12h, p12l, p21h, p21l,
                                    p22h, p22l, p31h, p31l, p32h, p32l);
    // ---- CSR build (scanB folded into place) ----
    k_scanA2 <<<NBINS, 256, 0, stream>>>(counts, bintotal, rowptr, NBINS, N, E);
    k_place2 <<<NBLK,  256, 0, stream>>>(srci, dsti, ew, counts, bintotal,
                                         binstart, binbuf, E, NBINS);
    k_binsort<<<NBINS, 256, 0, stream>>>(binbuf, binstart, rowptr, csr, N);

    // ---- fused layers (double-buffered activations) ----
    k_fused<64,  true,  true ><<<gMlp, 256, 0, stream>>>(xb0, xb1, rowptr, csr,
                                                         p11h, p11l, b11, p12h, p12l, b12, N, E);
    k_fused<128, true,  true ><<<gMlp, 256, 0, stream>>>(xb1, xb0, rowptr, csr,
                                                         p21h, p21l, b21, p22h, p22l, b22, N, E);
    k_fused<64,  false, false><<<gMlp, 256, 0, stream>>>(xb0, outF, rowptr, csr,
                                                         p31h, p31l, b31, p32h, p32l, b32, N, E);
}

// Round 6
// 274.440 us; speedup vs baseline: 1.3323x; 1.0138x over previous
//
#include <hip/hip_runtime.h>
#include <math.h>

// ---------------------------------------------------------------------------
// GIN, 3 layers, N=100000, E=1000000, D=64, fp32 in/out.
// Round 15: single-batch gather, 4-wave tile. R14 post-mortem: VALU issue
// ~22us/layer (41% busy) + latency stalls; wave still had 2 serial gather
// batches and grid only 12.5K waves. Fix: block = 4 waves = ONE 16-node
// tile; each wave gathers 4 nodes (ONE csr->rows round trip), MLP split
// 4-ways across the tile's waves (phase-1 cg split, phase-2 one cg/wave).
// Grid -> 6250 blocks = 25000 waves (2x TLP), serial chain halved.
// CSR build + pre kernel unchanged from R14.
// ---------------------------------------------------------------------------

#define FEAT  64
#define BINW  128          // nodes per bin
#define BSH   7            // log2(BINW)
#define NBLK  256          // edge-partition blocks
#define SRCB  25           // bits for src in packed key (N < 2^25)

typedef __attribute__((ext_vector_type(8))) short bfrag;   // 8 bf16 (4 VGPRs)
typedef __attribute__((ext_vector_type(4))) float ffrag;   // 4 fp32 acc

__device__ __forceinline__ unsigned short f2bf_rne(float x) {
    union { float f; unsigned u; } v; v.f = x;
    unsigned r = (v.u + 0x7fffu + ((v.u >> 16) & 1u)) >> 16;
    return (unsigned short)r;
}
__device__ __forceinline__ float bf2f(unsigned short h) {
    union { unsigned u; float f; } v; v.u = ((unsigned)h) << 16;
    return v.f;
}

// ---------------- weight pack helper ---------------------------------------
__device__ __forceinline__ void pack_one(const float* __restrict__ w,
                                         unsigned short* __restrict__ hi,
                                         unsigned short* __restrict__ lo,
                                         int K, int Hc, int i) {
    int KF = K >> 5;
    int j    = i & 7;
    int lane = (i >> 3) & 63;
    int fb   = i >> 9;
    int kf   = fb % KF;
    int cg   = fb / KF;
    int k    = kf * 32 + ((lane >> 4) << 3) + j;
    int col  = cg * 16 + (lane & 15);
    float x = w[k * Hc + col];
    unsigned short h = f2bf_rne(x);
    hi[i] = h;
    lo[i] = f2bf_rne(x - bf2f(h));
}

// ---------------- pre: cvt + cnt + pack, one launch ------------------------
__global__ __launch_bounds__(256)
void k_pre(const float4* __restrict__ x4, ushort4* __restrict__ xb4,
           int n4, int gCvt,
           const int* __restrict__ dst, int* __restrict__ counts,
           int E, int NBINS,
           const float* w11, const float* w12, const float* w21,
           const float* w22, const float* w31, const float* w32,
           unsigned short* p11h, unsigned short* p11l,
           unsigned short* p12h, unsigned short* p12l,
           unsigned short* p21h, unsigned short* p21l,
           unsigned short* p22h, unsigned short* p22l,
           unsigned short* p31h, unsigned short* p31l,
           unsigned short* p32h, unsigned short* p32l) {
    __shared__ int h[1024];
    const int bb = blockIdx.x, tid = threadIdx.x;
    if (bb < gCvt) {
        int i = bb * 256 + tid;
        if (i < n4) {
            float4 v = x4[i];
            ushort4 o;
            o.x = f2bf_rne(v.x); o.y = f2bf_rne(v.y);
            o.z = f2bf_rne(v.z); o.w = f2bf_rne(v.w);
            xb4[i] = o;
        }
    } else if (bb < gCvt + NBLK) {
        const int b = bb - gCvt;
        for (int i = tid; i < NBINS; i += 256) h[i] = 0;
        __syncthreads();
        const int chunk = (E + NBLK - 1) / NBLK;
        const int ebeg = b * chunk;
        const int eend = (ebeg + chunk < E) ? ebeg + chunk : E;
        for (int e = ebeg + tid; e < eend; e += 256)
            atomicAdd(&h[dst[e] >> BSH], 1);          // LDS atomic
        __syncthreads();
        for (int i = tid; i < NBINS; i += 256)
            counts[i * NBLK + b] = h[i];
    } else {
        int i = (bb - gCvt - NBLK) * 256 + tid;       // 0..32767
        if      (i <  4096) pack_one(w11, p11h, p11l,  64,  64, i);
        else if (i <  8192) pack_one(w12, p12h, p12l,  64,  64, i - 4096);
        else if (i < 16384) pack_one(w21, p21h, p21l,  64, 128, i - 8192);
        else if (i < 24576) pack_one(w22, p22h, p22l, 128,  64, i - 16384);
        else if (i < 28672) pack_one(w31, p31h, p31l,  64,  64, i - 24576);
        else                pack_one(w32, p32h, p32l,  64,  64, i - 28672);
    }
}

// ---------------- per-bin scan over the 256 partition blocks ---------------
__global__ __launch_bounds__(256)
void k_scanA2(int* __restrict__ counts, int* __restrict__ bintotal,
              int* __restrict__ rowptr, int NBINS, int N, int E) {
    __shared__ int tmp[256];
    const int bin = blockIdx.x, tid = threadIdx.x;
    int c = counts[bin * NBLK + tid];
    tmp[tid] = c;
    __syncthreads();
    for (int off = 1; off < 256; off <<= 1) {
        int t = (tid >= off) ? tmp[tid - off] : 0;
        __syncthreads();
        tmp[tid] += t;
        __syncthreads();
    }
    counts[bin * NBLK + tid] = tmp[tid] - c;      // exclusive within bin
    if (tid == 255) bintotal[bin] = tmp[255];
    if (bin == 0 && tid == 0) rowptr[N] = E;
}

// ---------------- place edges (local binstart scan, no scanB) --------------
__global__ __launch_bounds__(256)
void k_place2(const int* __restrict__ src, const int* __restrict__ dst,
              const float* __restrict__ ew, const int* __restrict__ counts,
              const int* __restrict__ bintotal, int* __restrict__ binstart,
              int2* __restrict__ binbuf, int E, int NBINS) {
    __shared__ int bs[1024];        // local exclusive prefix of bintotal
    __shared__ int tmp[256];
    __shared__ int base[1024];
    const int b = blockIdx.x, tid = threadIdx.x;

    int v[4]; int s = 0;
#pragma unroll
    for (int j = 0; j < 4; ++j) {
        int idx = tid * 4 + j;
        v[j] = (idx < NBINS) ? bintotal[idx] : 0;
        s += v[j];
    }
    tmp[tid] = s;
    __syncthreads();
    for (int off = 1; off < 256; off <<= 1) {
        int t = (tid >= off) ? tmp[tid - off] : 0;
        __syncthreads();
        tmp[tid] += t;
        __syncthreads();
    }
    int run = tmp[tid] - s;
#pragma unroll
    for (int j = 0; j < 4; ++j) {
        bs[tid * 4 + j] = run;
        run += v[j];
    }
    __syncthreads();

    if (b == 0) {
        for (int i = tid; i < NBINS; i += 256) binstart[i] = bs[i];
        if (tid == 0) binstart[NBINS] = E;
    }

    for (int i = tid; i < NBINS; i += 256)
        base[i] = bs[i] + counts[i * NBLK + b];
    __syncthreads();

    const int chunk = (E + NBLK - 1) / NBLK;
    const int ebeg = b * chunk;
    const int eend = (ebeg + chunk < E) ? ebeg + chunk : E;
    for (int e = ebeg + tid; e < eend; e += 256) {
        int d = dst[e];
        int slot = atomicAdd(&base[d >> BSH], 1);   // LDS atomic only
        int key = ((d & (BINW - 1)) << SRCB) | src[e];
        binbuf[slot] = make_int2(key, __float_as_int(ew[e]));
    }
}

// one block per bin: count 128 nodes -> scan -> rowptr -> place edges.
__global__ __launch_bounds__(256)
void k_binsort(const int2* __restrict__ binbuf, const int* __restrict__ binstart,
               int* __restrict__ rowptr, int2* __restrict__ csr, int N) {
    __shared__ int cnt[BINW];
    __shared__ int cur[BINW];
    const int b    = blockIdx.x;
    const int base = binstart[b];
    const int ne   = binstart[b + 1] - base;
    const int tid  = threadIdx.x;

    if (tid < BINW) cnt[tid] = 0;
    __syncthreads();
    for (int i = tid; i < ne; i += 256)
        atomicAdd(&cnt[(binbuf[base + i].x >> SRCB) & (BINW - 1)], 1);
    __syncthreads();
    if (tid < BINW) cur[tid] = cnt[tid];
    __syncthreads();
    for (int off = 1; off < BINW; off <<= 1) {
        int v = (tid < BINW && tid >= off) ? cur[tid - off] : 0;
        __syncthreads();
        if (tid < BINW) cur[tid] += v;
        __syncthreads();
    }
    if (tid < BINW) {
        int ex = cur[tid] - cnt[tid];
        int node = b * BINW + tid;
        if (node < N) rowptr[node] = base + ex;
        cur[tid] = ex;
    }
    __syncthreads();
    for (int i = tid; i < ne; i += 256) {
        int2 e = binbuf[base + i];
        int dl = (e.x >> SRCB) & (BINW - 1);
        int r = atomicAdd(&cur[dl], 1);
        csr[base + r] = make_int2(e.x & ((1 << SRCB) - 1), e.y);
    }
}

// ---------------- fused gather + MLP (4-wave tile, 1 gather batch) ---------
// Block = 4 waves = ONE 16-node tile. Wave wk gathers nodes tnode0+wk*4+q
// (one node per 16-lane group, 16 edges in flight, single csr->rows round
// trip). MLP split 4 ways: phase-1 col-groups wk*CGH1..; phase-2 cg = wk.
template<int H, bool RELU_OUT, bool OUT_BF16>
__global__ __launch_bounds__(256)
void k_fused(const ushort* __restrict__ in, void* __restrict__ outv,
             const int* __restrict__ rowptr, const int2* __restrict__ csr,
             const unsigned short* __restrict__ w1h, const unsigned short* __restrict__ w1l,
             const float* __restrict__ b1,
             const unsigned short* __restrict__ w2h, const unsigned short* __restrict__ w2l,
             const float* __restrict__ b2, int N, int E) {
    constexpr int SH   = H + 4;      // LDS h-row stride
    constexpr int CG1  = H / 16;     // phase-1 col groups (split across 4 waves)
    constexpr int CGH1 = CG1 / 4;    // per-wave phase-1 col groups
    constexpr int KF2  = H / 32;     // phase-2 k frags
    __shared__ float hs[16 * SH];    // one 16-node tile

    const int t = threadIdx.x;
    const int wk = t >> 6, lane = t & 63;     // wave-in-tile 0..3
    const int m = lane & 15, q = lane >> 4;
    const int tnode0 = blockIdx.x * 16;
    float* hw = hs;
    const ushort4* in4 = reinterpret_cast<const ushort4*>(in);

    // ---- preload rowptr boundaries for this wave's 4 nodes (one load) ----
    int rp_l = 0;
    {
        int idx = tnode0 + wk * 4 + lane;
        if (lane <= 4) rp_l = rowptr[idx <= N ? idx : N];
    }

    // ---- hoist "+x" row ----
    int gnode = tnode0 + wk * 4 + q;
    int gnodeC = gnode < N ? gnode : N - 1;
    ushort4 xr = in4[(size_t)gnodeC * 16 + m];

    // ---- gather: 4 nodes in parallel per wave, 16 edges in flight/group ----
    {
        const int nl  = wk * 4 + q;               // row within tile 0..15
        const int beg = __shfl(rp_l, q);
        const int end = __shfl(rp_l, q + 1);
        float4 acc = make_float4(0.f, 0.f, 0.f, 0.f);
        for (int p = beg; p < end; p += 16) {
            int   s[16];
            float w[16];
#pragma unroll
            for (int u = 0; u < 16; ++u) {
                int i = p + u;
                int2 ev = csr[i < E ? i : E - 1];   // always issued
                s[u] = ev.x;
                w[u] = (i < end) ? __int_as_float(ev.y) : 0.f;
            }
            ushort4 v4[16];
#pragma unroll
            for (int u = 0; u < 16; ++u)
                v4[u] = in4[(unsigned)s[u] * 16u + m];   // 16 rows in flight
#pragma unroll
            for (int u = 0; u < 16; ++u) {
                acc.x = fmaf(w[u], bf2f(v4[u].x), acc.x);
                acc.y = fmaf(w[u], bf2f(v4[u].y), acc.y);
                acc.z = fmaf(w[u], bf2f(v4[u].z), acc.z);
                acc.w = fmaf(w[u], bf2f(v4[u].w), acc.w);
            }
        }
        acc.x += bf2f(xr.x); acc.y += bf2f(xr.y);
        acc.z += bf2f(xr.z); acc.w += bf2f(xr.w);
        *reinterpret_cast<float4*>(&hw[nl * SH + m * 4]) = acc;
    }
    __syncthreads();   // tile rows complete (all 4 waves)

    // ---- A frags (K=64 -> 2 kf) from shared tile, split hi/lo ----
    const bfrag* w1hp = reinterpret_cast<const bfrag*>(w1h);
    const bfrag* w1lp = reinterpret_cast<const bfrag*>(w1l);
    const bfrag* w2hp = reinterpret_cast<const bfrag*>(w2h);
    const bfrag* w2lp = reinterpret_cast<const bfrag*>(w2l);

    bfrag ah[2], al[2];
#pragma unroll
    for (int kf = 0; kf < 2; ++kf) {
        const float* base = &hw[m * SH + kf * 32 + q * 8];
        float4 u0 = *reinterpret_cast<const float4*>(base);
        float4 u1 = *reinterpret_cast<const float4*>(base + 4);
        float u[8] = {u0.x, u0.y, u0.z, u0.w, u1.x, u1.y, u1.z, u1.w};
#pragma unroll
        for (int j = 0; j < 8; ++j) {
            unsigned short hb = f2bf_rne(u[j]);
            ah[kf][j] = (short)hb;
            al[kf][j] = (short)f2bf_rne(u[j] - bf2f(hb));
        }
    }
    __syncthreads();   // all A-frags read before h overwrites the tile

    // ---- phase 1: h = relu(A@W1 + b1) -> LDS (cg split across 4 waves) ----
#pragma unroll
    for (int cgi = 0; cgi < CGH1; ++cgi) {
        const int cg = wk * CGH1 + cgi;
        ffrag c = {0.f, 0.f, 0.f, 0.f};
#pragma unroll
        for (int kf = 0; kf < 2; ++kf) {
            bfrag bh = w1hp[(cg * 2 + kf) * 64 + lane];
            bfrag bl = w1lp[(cg * 2 + kf) * 64 + lane];
            c = __builtin_amdgcn_mfma_f32_16x16x32_bf16(ah[kf], bh, c, 0, 0, 0);
            c = __builtin_amdgcn_mfma_f32_16x16x32_bf16(al[kf], bh, c, 0, 0, 0);
            c = __builtin_amdgcn_mfma_f32_16x16x32_bf16(ah[kf], bl, c, 0, 0, 0);
        }
        float bias = b1[cg * 16 + m];
#pragma unroll
        for (int r = 0; r < 4; ++r) {
            float hv = fmaxf(c[r] + bias, 0.f);
            hw[(q * 4 + r) * SH + cg * 16 + m] = hv;   // row=node, col=h-col
        }
    }
    __syncthreads();   // h complete (all 4 waves)

    // ---- h -> A frags (hi/lo), full K per wave ----
    bfrag gh[KF2], gl[KF2];
#pragma unroll
    for (int kf = 0; kf < KF2; ++kf) {
        const float* base = &hw[m * SH + kf * 32 + q * 8];
        float4 u0 = *reinterpret_cast<const float4*>(base);
        float4 u1 = *reinterpret_cast<const float4*>(base + 4);
        float u[8] = {u0.x, u0.y, u0.z, u0.w, u1.x, u1.y, u1.z, u1.w};
#pragma unroll
        for (int j = 0; j < 8; ++j) {
            unsigned short hb = f2bf_rne(u[j]);
            gh[kf][j] = (short)hb;
            gl[kf][j] = (short)f2bf_rne(u[j] - bf2f(hb));
        }
    }

    // ---- phase 2: out = h@W2 + b2 (one output cg per wave) ----
    {
        const int cg = wk;
        ffrag c = {0.f, 0.f, 0.f, 0.f};
#pragma unroll
        for (int kf = 0; kf < KF2; ++kf) {
            bfrag bh = w2hp[(cg * KF2 + kf) * 64 + lane];
            bfrag bl = w2lp[(cg * KF2 + kf) * 64 + lane];
            c = __builtin_amdgcn_mfma_f32_16x16x32_bf16(gh[kf], bh, c, 0, 0, 0);
            c = __builtin_amdgcn_mfma_f32_16x16x32_bf16(gl[kf], bh, c, 0, 0, 0);
            c = __builtin_amdgcn_mfma_f32_16x16x32_bf16(gh[kf], bl, c, 0, 0, 0);
        }
        float bias = b2[cg * 16 + m];
#pragma unroll
        for (int r = 0; r < 4; ++r) {
            int nd = tnode0 + q * 4 + r;
            if (nd < N) {
                float v = c[r] + bias;
                if (RELU_OUT) v = fmaxf(v, 0.f);
                if (OUT_BF16)
                    ((unsigned short*)outv)[(size_t)nd * FEAT + cg * 16 + m] = f2bf_rne(v);
                else
                    ((float*)outv)[(size_t)nd * FEAT + cg * 16 + m] = v;
            }
        }
    }
}

// ---------------------------------------------------------------------------
extern "C" void kernel_launch(void* const* d_in, const int* in_sizes, int n_in,
                              void* d_out, int out_size, void* d_ws, size_t ws_size,
                              hipStream_t stream) {
    const float* x   = (const float*)d_in[0];
    const int*   ei  = (const int*)  d_in[1];
    const float* ew  = (const float*)d_in[2];
    const float* w11 = (const float*)d_in[3];
    const float* b11 = (const float*)d_in[4];
    const float* w12 = (const float*)d_in[5];
    const float* b12 = (const float*)d_in[6];
    const float* w21 = (const float*)d_in[7];
    const float* b21 = (const float*)d_in[8];
    const float* w22 = (const float*)d_in[9];
    const float* b22 = (const float*)d_in[10];
    const float* w31 = (const float*)d_in[11];
    const float* b31 = (const float*)d_in[12];
    const float* w32 = (const float*)d_in[13];
    const float* b32 = (const float*)d_in[14];

    const int N = in_sizes[0] / FEAT;   // 100000
    const int E = in_sizes[2];          // 1000000
    const int* srci = ei;
    const int* dsti = ei + E;
    const int NBINS = (N + BINW - 1) >> BSH;   // 782

    // ---- workspace layout ----
    unsigned short* xb0 = (unsigned short*)d_ws;             // [N*64] bf16
    unsigned short* xb1 = xb0 + (size_t)N * FEAT;            // [N*64] bf16
    int*   rowptr   = (int*)(xb1 + (size_t)N * FEAT);        // [N+1]
    int*   counts   = rowptr + (N + 1);                      // [NBINS*NBLK]
    int*   bintotal = counts + NBINS * NBLK;                 // [NBINS]
    int*   binstart = bintotal + NBINS;                      // [NBINS+1]
    size_t a16 = ((size_t)(binstart + NBINS + 1) + 15) & ~(size_t)15;
    int2*  binbuf   = (int2*)a16;                            // [E] (key, w)
    int2*  csr      = (int2*)(binbuf + E);                   // [E] (src, w)
    size_t pk = (size_t)(csr + E);
    unsigned short* p11h = (unsigned short*)pk;              // 4096 each for 64x64
    unsigned short* p11l = p11h + 4096;
    unsigned short* p12h = p11l + 4096;
    unsigned short* p12l = p12h + 4096;
    unsigned short* p21h = p12l + 4096;                      // 8192 for 64x128
    unsigned short* p21l = p21h + 8192;
    unsigned short* p22h = p21l + 8192;                      // 8192 for 128x64
    unsigned short* p22l = p22h + 8192;
    unsigned short* p31h = p22l + 8192;
    unsigned short* p31l = p31h + 4096;
    unsigned short* p32h = p31l + 4096;
    unsigned short* p32l = p32h + 4096;
    float* outF = (float*)d_out;                             // [N*64]

    const int n4   = N * 16;
    const int gCvt = (n4 + 255) / 256;
    const int gMlp = (N + 15) / 16;            // 6250 blocks, 25000 waves
    const int gPre = gCvt + NBLK + 128;

    // ---- pre: cvt + histogram + weight pack (one launch) ----
    k_pre<<<gPre, 256, 0, stream>>>((const float4*)x, (ushort4*)xb0, n4, gCvt,
                                    dsti, counts, E, NBINS,
                                    w11, w12, w21, w22, w31, w32,
                                    p11h, p11l, p12h, p12l, p21h, p21l,
                                    p22h, p22l, p31h, p31l, p32h, p32l);
    // ---- CSR build (scanB folded into place) ----
    k_scanA2 <<<NBINS, 256, 0, stream>>>(counts, bintotal, rowptr, NBINS, N, E);
    k_place2 <<<NBLK,  256, 0, stream>>>(srci, dsti, ew, counts, bintotal,
                                         binstart, binbuf, E, NBINS);
    k_binsort<<<NBINS, 256, 0, stream>>>(binbuf, binstart, rowptr, csr, N);

    // ---- fused layers (double-buffered activations) ----
    k_fused<64,  true,  true ><<<gMlp, 256, 0, stream>>>(xb0, xb1, rowptr, csr,
                                                         p11h, p11l, b11, p12h, p12l, b12, N, E);
    k_fused<128, true,  true ><<<gMlp, 256, 0, stream>>>(xb1, xb0, rowptr, csr,
                                                         p21h, p21l, b21, p22h, p22l, b22, N, E);
    k_fused<64,  false, false><<<gMlp, 256, 0, stream>>>(xb0, outF, rowptr, csr,
                                                         p31h, p31l, b31, p32h, p32l, b32, N, E);
}

// Round 7
// 263.131 us; speedup vs baseline: 1.3896x; 1.0430x over previous
//
#include <hip/hip_runtime.h>
#include <math.h>

// ---------------------------------------------------------------------------
// GIN, 3 layers, N=100000, E=1000000, D=64, fp32 in/out.
// Round 16: VALU-cut in the gather inner loop. R15 post-mortem: VALUBusy 51%
// -> issue-bound, ~272 VALU/iter dominated by per-edge clamps/selects and
// 16x 8B csr loads. Fix:
//   - CSR padded to multiples of 16 entries per node (zero-weight, src=0)
//     at build time (k_binsort): gather loop has NO conditionals at all.
//     Accumulation order for real edges unchanged (fmaf(0,x,acc) exact).
//   - csr read as 8x int4 (16B, edge pairs) from a 16-entry-aligned padded
//     base: address computes fold into load immediate offsets.
//   - pbeg/pend arrays (padded begin/end per node) replace rowptr+shfl.
//   - s_setprio(1) around MFMA clusters.
// Everything else (pre kernel, cnt/scan/place, fused MLP phases) unchanged.
// ---------------------------------------------------------------------------

#define FEAT  64
#define BINW  128          // nodes per bin
#define BSH   7            // log2(BINW)
#define NBLK  256          // edge-partition blocks
#define SRCB  25           // bits for src in packed key (N < 2^25)
#define PADSLACK 2048      // per-bin slack for padding (>= 128*15 + 16)

typedef __attribute__((ext_vector_type(8))) short bfrag;   // 8 bf16 (4 VGPRs)
typedef __attribute__((ext_vector_type(4))) float ffrag;   // 4 fp32 acc

__device__ __forceinline__ unsigned short f2bf_rne(float x) {
    union { float f; unsigned u; } v; v.f = x;
    unsigned r = (v.u + 0x7fffu + ((v.u >> 16) & 1u)) >> 16;
    return (unsigned short)r;
}
__device__ __forceinline__ float bf2f(unsigned short h) {
    union { unsigned u; float f; } v; v.u = ((unsigned)h) << 16;
    return v.f;
}

// ---------------- weight pack helper ---------------------------------------
__device__ __forceinline__ void pack_one(const float* __restrict__ w,
                                         unsigned short* __restrict__ hi,
                                         unsigned short* __restrict__ lo,
                                         int K, int Hc, int i) {
    int KF = K >> 5;
    int j    = i & 7;
    int lane = (i >> 3) & 63;
    int fb   = i >> 9;
    int kf   = fb % KF;
    int cg   = fb / KF;
    int k    = kf * 32 + ((lane >> 4) << 3) + j;
    int col  = cg * 16 + (lane & 15);
    float x = w[k * Hc + col];
    unsigned short h = f2bf_rne(x);
    hi[i] = h;
    lo[i] = f2bf_rne(x - bf2f(h));
}

// ---------------- pre: cvt + cnt + pack, one launch ------------------------
__global__ __launch_bounds__(256)
void k_pre(const float4* __restrict__ x4, ushort4* __restrict__ xb4,
           int n4, int gCvt,
           const int* __restrict__ dst, int* __restrict__ counts,
           int E, int NBINS,
           const float* w11, const float* w12, const float* w21,
           const float* w22, const float* w31, const float* w32,
           unsigned short* p11h, unsigned short* p11l,
           unsigned short* p12h, unsigned short* p12l,
           unsigned short* p21h, unsigned short* p21l,
           unsigned short* p22h, unsigned short* p22l,
           unsigned short* p31h, unsigned short* p31l,
           unsigned short* p32h, unsigned short* p32l) {
    __shared__ int h[1024];
    const int bb = blockIdx.x, tid = threadIdx.x;
    if (bb < gCvt) {
        int i = bb * 256 + tid;
        if (i < n4) {
            float4 v = x4[i];
            ushort4 o;
            o.x = f2bf_rne(v.x); o.y = f2bf_rne(v.y);
            o.z = f2bf_rne(v.z); o.w = f2bf_rne(v.w);
            xb4[i] = o;
        }
    } else if (bb < gCvt + NBLK) {
        const int b = bb - gCvt;
        for (int i = tid; i < NBINS; i += 256) h[i] = 0;
        __syncthreads();
        const int chunk = (E + NBLK - 1) / NBLK;
        const int ebeg = b * chunk;
        const int eend = (ebeg + chunk < E) ? ebeg + chunk : E;
        for (int e = ebeg + tid; e < eend; e += 256)
            atomicAdd(&h[dst[e] >> BSH], 1);          // LDS atomic
        __syncthreads();
        for (int i = tid; i < NBINS; i += 256)
            counts[i * NBLK + b] = h[i];
    } else {
        int i = (bb - gCvt - NBLK) * 256 + tid;       // 0..32767
        if      (i <  4096) pack_one(w11, p11h, p11l,  64,  64, i);
        else if (i <  8192) pack_one(w12, p12h, p12l,  64,  64, i - 4096);
        else if (i < 16384) pack_one(w21, p21h, p21l,  64, 128, i - 8192);
        else if (i < 24576) pack_one(w22, p22h, p22l, 128,  64, i - 16384);
        else if (i < 28672) pack_one(w31, p31h, p31l,  64,  64, i - 24576);
        else                pack_one(w32, p32h, p32l,  64,  64, i - 28672);
    }
}

// ---------------- per-bin scan over the 256 partition blocks ---------------
__global__ __launch_bounds__(256)
void k_scanA2(int* __restrict__ counts, int* __restrict__ bintotal, int NBINS) {
    __shared__ int tmp[256];
    const int bin = blockIdx.x, tid = threadIdx.x;
    int c = counts[bin * NBLK + tid];
    tmp[tid] = c;
    __syncthreads();
    for (int off = 1; off < 256; off <<= 1) {
        int t = (tid >= off) ? tmp[tid - off] : 0;
        __syncthreads();
        tmp[tid] += t;
        __syncthreads();
    }
    counts[bin * NBLK + tid] = tmp[tid] - c;      // exclusive within bin
    if (tid == 255) bintotal[bin] = tmp[255];
}

// ---------------- place edges (local binstart scan, no scanB) --------------
__global__ __launch_bounds__(256)
void k_place2(const int* __restrict__ src, const int* __restrict__ dst,
              const float* __restrict__ ew, const int* __restrict__ counts,
              const int* __restrict__ bintotal, int* __restrict__ binstart,
              int2* __restrict__ binbuf, int E, int NBINS) {
    __shared__ int bs[1024];        // local exclusive prefix of bintotal
    __shared__ int tmp[256];
    __shared__ int base[1024];
    const int b = blockIdx.x, tid = threadIdx.x;

    int v[4]; int s = 0;
#pragma unroll
    for (int j = 0; j < 4; ++j) {
        int idx = tid * 4 + j;
        v[j] = (idx < NBINS) ? bintotal[idx] : 0;
        s += v[j];
    }
    tmp[tid] = s;
    __syncthreads();
    for (int off = 1; off < 256; off <<= 1) {
        int t = (tid >= off) ? tmp[tid - off] : 0;
        __syncthreads();
        tmp[tid] += t;
        __syncthreads();
    }
    int run = tmp[tid] - s;
#pragma unroll
    for (int j = 0; j < 4; ++j) {
        bs[tid * 4 + j] = run;
        run += v[j];
    }
    __syncthreads();

    if (b == 0) {
        for (int i = tid; i < NBINS; i += 256) binstart[i] = bs[i];
        if (tid == 0) binstart[NBINS] = E;
    }

    for (int i = tid; i < NBINS; i += 256)
        base[i] = bs[i] + counts[i * NBLK + b];
    __syncthreads();

    const int chunk = (E + NBLK - 1) / NBLK;
    const int ebeg = b * chunk;
    const int eend = (ebeg + chunk < E) ? ebeg + chunk : E;
    for (int e = ebeg + tid; e < eend; e += 256) {
        int d = dst[e];
        int slot = atomicAdd(&base[d >> BSH], 1);   // LDS atomic only
        int key = ((d & (BINW - 1)) << SRCB) | src[e];
        binbuf[slot] = make_int2(key, __float_as_int(ew[e]));
    }
}

// one block per bin: count -> padded scan -> pbeg/pend -> place + pad fill.
__global__ __launch_bounds__(256)
void k_binsort(const int2* __restrict__ binbuf, const int* __restrict__ binstart,
               int* __restrict__ pbeg, int* __restrict__ pend,
               int2* __restrict__ csr_pad, int N) {
    __shared__ int cnt[BINW];
    __shared__ int cur[BINW];
    __shared__ int pex[BINW];
    const int b    = blockIdx.x;
    const int base = binstart[b];
    const int ne   = binstart[b + 1] - base;
    const int tid  = threadIdx.x;
    const int base_pad = ((base + 15) & ~15) + b * PADSLACK;  // 16-aligned

    if (tid < BINW) cnt[tid] = 0;
    __syncthreads();
    for (int i = tid; i < ne; i += 256)
        atomicAdd(&cnt[(binbuf[base + i].x >> SRCB) & (BINW - 1)], 1);
    __syncthreads();
    int pc = 0;
    if (tid < BINW) { pc = (cnt[tid] + 15) & ~15; cur[tid] = pc; }
    __syncthreads();
    for (int off = 1; off < BINW; off <<= 1) {
        int v = (tid < BINW && tid >= off) ? cur[tid - off] : 0;
        __syncthreads();
        if (tid < BINW) cur[tid] += v;
        __syncthreads();
    }
    if (tid < BINW) {
        int ex = cur[tid] - pc;            // exclusive padded prefix
        pex[tid] = ex;
        int node = b * BINW + tid;
        if (node < N) {
            pbeg[node] = base_pad + ex;
            pend[node] = base_pad + ex + pc;
        }
        cur[tid] = 0;                      // rank cursor
    }
    __syncthreads();
    for (int i = tid; i < ne; i += 256) {
        int2 e = binbuf[base + i];
        int dl = (e.x >> SRCB) & (BINW - 1);
        int r = atomicAdd(&cur[dl], 1);
        csr_pad[base_pad + pex[dl] + r] = make_int2(e.x & ((1 << SRCB) - 1), e.y);
    }
    __syncthreads();
    if (tid < BINW) {                      // zero-weight padding entries
        int c = cnt[tid];
        int pcn = (c + 15) & ~15;
        int o = base_pad + pex[tid];
        for (int j = c; j < pcn; ++j)
            csr_pad[o + j] = make_int2(0, 0);
    }
}

// ---------------- fused gather + MLP (4-wave tile, padded CSR) -------------
// Block = 4 waves = ONE 16-node tile. Wave wk gathers nodes tnode0+wk*4+q
// (one node per 16-lane group, 16 edges in flight via 8x int4 loads, no
// conditionals). MLP split 4 ways: phase-1 cg wk*CGH1..; phase-2 cg = wk.
template<int H, bool RELU_OUT, bool OUT_BF16>
__global__ __launch_bounds__(256)
void k_fused(const ushort* __restrict__ in, void* __restrict__ outv,
             const int* __restrict__ pbeg, const int* __restrict__ pend,
             const int2* __restrict__ csr_pad,
             const unsigned short* __restrict__ w1h, const unsigned short* __restrict__ w1l,
             const float* __restrict__ b1,
             const unsigned short* __restrict__ w2h, const unsigned short* __restrict__ w2l,
             const float* __restrict__ b2, int N) {
    constexpr int SH   = H + 4;      // LDS h-row stride
    constexpr int CG1  = H / 16;     // phase-1 col groups (split across 4 waves)
    constexpr int CGH1 = CG1 / 4;    // per-wave phase-1 col groups
    constexpr int KF2  = H / 32;     // phase-2 k frags
    __shared__ float hs[16 * SH];    // one 16-node tile

    const int t = threadIdx.x;
    const int wk = t >> 6, lane = t & 63;     // wave-in-tile 0..3
    const int m = lane & 15, q = lane >> 4;
    const int tnode0 = blockIdx.x * 16;
    float* hw = hs;
    const ushort4* in4 = reinterpret_cast<const ushort4*>(in);
    const int4* csr4 = reinterpret_cast<const int4*>(csr_pad);

    // N % 16 == 0: every node in every tile is valid.
    const int gnode = tnode0 + wk * 4 + q;
    const int beg = pbeg[gnode];              // broadcast within 16-lane group
    const int end = pend[gnode];
    ushort4 xr = in4[(size_t)gnode * 16 + m]; // "+x" row, issue early

    // ---- gather: 4 nodes in parallel per wave, 16 edges in flight/group ----
    {
        const int nl = wk * 4 + q;            // row within tile 0..15
        float4 acc = make_float4(0.f, 0.f, 0.f, 0.f);
        for (int p = beg; p < end; p += 16) {
            int4 e2[8];
#pragma unroll
            for (int u = 0; u < 8; ++u)
                e2[u] = csr4[(p >> 1) + u];   // 2 edges per 16B load
            ushort4 v4[16];
#pragma unroll
            for (int u = 0; u < 8; ++u) {
                v4[2*u]   = in4[(unsigned)e2[u].x * 16u + m];
                v4[2*u+1] = in4[(unsigned)e2[u].z * 16u + m];
            }
#pragma unroll
            for (int u = 0; u < 8; ++u) {
                float w0 = __int_as_float(e2[u].y);
                float w1 = __int_as_float(e2[u].w);
                acc.x = fmaf(w0, bf2f(v4[2*u].x), acc.x);
                acc.y = fmaf(w0, bf2f(v4[2*u].y), acc.y);
                acc.z = fmaf(w0, bf2f(v4[2*u].z), acc.z);
                acc.w = fmaf(w0, bf2f(v4[2*u].w), acc.w);
                acc.x = fmaf(w1, bf2f(v4[2*u+1].x), acc.x);
                acc.y = fmaf(w1, bf2f(v4[2*u+1].y), acc.y);
                acc.z = fmaf(w1, bf2f(v4[2*u+1].z), acc.z);
                acc.w = fmaf(w1, bf2f(v4[2*u+1].w), acc.w);
            }
        }
        acc.x += bf2f(xr.x); acc.y += bf2f(xr.y);
        acc.z += bf2f(xr.z); acc.w += bf2f(xr.w);
        *reinterpret_cast<float4*>(&hw[nl * SH + m * 4]) = acc;
    }
    __syncthreads();   // tile rows complete (all 4 waves)

    // ---- A frags (K=64 -> 2 kf) from shared tile, split hi/lo ----
    const bfrag* w1hp = reinterpret_cast<const bfrag*>(w1h);
    const bfrag* w1lp = reinterpret_cast<const bfrag*>(w1l);
    const bfrag* w2hp = reinterpret_cast<const bfrag*>(w2h);
    const bfrag* w2lp = reinterpret_cast<const bfrag*>(w2l);

    bfrag ah[2], al[2];
#pragma unroll
    for (int kf = 0; kf < 2; ++kf) {
        const float* base = &hw[m * SH + kf * 32 + q * 8];
        float4 u0 = *reinterpret_cast<const float4*>(base);
        float4 u1 = *reinterpret_cast<const float4*>(base + 4);
        float u[8] = {u0.x, u0.y, u0.z, u0.w, u1.x, u1.y, u1.z, u1.w};
#pragma unroll
        for (int j = 0; j < 8; ++j) {
            unsigned short hb = f2bf_rne(u[j]);
            ah[kf][j] = (short)hb;
            al[kf][j] = (short)f2bf_rne(u[j] - bf2f(hb));
        }
    }
    __syncthreads();   // all A-frags read before h overwrites the tile

    // ---- phase 1: h = relu(A@W1 + b1) -> LDS (cg split across 4 waves) ----
    __builtin_amdgcn_s_setprio(1);
#pragma unroll
    for (int cgi = 0; cgi < CGH1; ++cgi) {
        const int cg = wk * CGH1 + cgi;
        ffrag c = {0.f, 0.f, 0.f, 0.f};
#pragma unroll
        for (int kf = 0; kf < 2; ++kf) {
            bfrag bh = w1hp[(cg * 2 + kf) * 64 + lane];
            bfrag bl = w1lp[(cg * 2 + kf) * 64 + lane];
            c = __builtin_amdgcn_mfma_f32_16x16x32_bf16(ah[kf], bh, c, 0, 0, 0);
            c = __builtin_amdgcn_mfma_f32_16x16x32_bf16(al[kf], bh, c, 0, 0, 0);
            c = __builtin_amdgcn_mfma_f32_16x16x32_bf16(ah[kf], bl, c, 0, 0, 0);
        }
        float bias = b1[cg * 16 + m];
#pragma unroll
        for (int r = 0; r < 4; ++r) {
            float hv = fmaxf(c[r] + bias, 0.f);
            hw[(q * 4 + r) * SH + cg * 16 + m] = hv;   // row=node, col=h-col
        }
    }
    __builtin_amdgcn_s_setprio(0);
    __syncthreads();   // h complete (all 4 waves)

    // ---- h -> A frags (hi/lo), full K per wave ----
    bfrag gh[KF2], gl[KF2];
#pragma unroll
    for (int kf = 0; kf < KF2; ++kf) {
        const float* base = &hw[m * SH + kf * 32 + q * 8];
        float4 u0 = *reinterpret_cast<const float4*>(base);
        float4 u1 = *reinterpret_cast<const float4*>(base + 4);
        float u[8] = {u0.x, u0.y, u0.z, u0.w, u1.x, u1.y, u1.z, u1.w};
#pragma unroll
        for (int j = 0; j < 8; ++j) {
            unsigned short hb = f2bf_rne(u[j]);
            gh[kf][j] = (short)hb;
            gl[kf][j] = (short)f2bf_rne(u[j] - bf2f(hb));
        }
    }

    // ---- phase 2: out = h@W2 + b2 (one output cg per wave) ----
    {
        const int cg = wk;
        ffrag c = {0.f, 0.f, 0.f, 0.f};
        __builtin_amdgcn_s_setprio(1);
#pragma unroll
        for (int kf = 0; kf < KF2; ++kf) {
            bfrag bh = w2hp[(cg * KF2 + kf) * 64 + lane];
            bfrag bl = w2lp[(cg * KF2 + kf) * 64 + lane];
            c = __builtin_amdgcn_mfma_f32_16x16x32_bf16(gh[kf], bh, c, 0, 0, 0);
            c = __builtin_amdgcn_mfma_f32_16x16x32_bf16(gl[kf], bh, c, 0, 0, 0);
            c = __builtin_amdgcn_mfma_f32_16x16x32_bf16(gh[kf], bl, c, 0, 0, 0);
        }
        __builtin_amdgcn_s_setprio(0);
        float bias = b2[cg * 16 + m];
#pragma unroll
        for (int r = 0; r < 4; ++r) {
            int nd = tnode0 + q * 4 + r;
            if (nd < N) {
                float v = c[r] + bias;
                if (RELU_OUT) v = fmaxf(v, 0.f);
                if (OUT_BF16)
                    ((unsigned short*)outv)[(size_t)nd * FEAT + cg * 16 + m] = f2bf_rne(v);
                else
                    ((float*)outv)[(size_t)nd * FEAT + cg * 16 + m] = v;
            }
        }
    }
}

// ---------------------------------------------------------------------------
extern "C" void kernel_launch(void* const* d_in, const int* in_sizes, int n_in,
                              void* d_out, int out_size, void* d_ws, size_t ws_size,
                              hipStream_t stream) {
    const float* x   = (const float*)d_in[0];
    const int*   ei  = (const int*)  d_in[1];
    const float* ew  = (const float*)d_in[2];
    const float* w11 = (const float*)d_in[3];
    const float* b11 = (const float*)d_in[4];
    const float* w12 = (const float*)d_in[5];
    const float* b12 = (const float*)d_in[6];
    const float* w21 = (const float*)d_in[7];
    const float* b21 = (const float*)d_in[8];
    const float* w22 = (const float*)d_in[9];
    const float* b22 = (const float*)d_in[10];
    const float* w31 = (const float*)d_in[11];
    const float* b31 = (const float*)d_in[12];
    const float* w32 = (const float*)d_in[13];
    const float* b32 = (const float*)d_in[14];

    const int N = in_sizes[0] / FEAT;   // 100000
    const int E = in_sizes[2];          // 1000000
    const int* srci = ei;
    const int* dsti = ei + E;
    const int NBINS = (N + BINW - 1) >> BSH;   // 782

    // ---- workspace layout ----
    unsigned short* xb0 = (unsigned short*)d_ws;             // [N*64] bf16
    unsigned short* xb1 = xb0 + (size_t)N * FEAT;            // [N*64] bf16
    int*   pbeg     = (int*)(xb1 + (size_t)N * FEAT);        // [N]
    int*   pend     = pbeg + N;                              // [N]
    int*   counts   = pend + N;                              // [NBINS*NBLK]
    int*   bintotal = counts + NBINS * NBLK;                 // [NBINS]
    int*   binstart = bintotal + NBINS;                      // [NBINS+1]
    size_t a16 = ((size_t)(binstart + NBINS + 1) + 15) & ~(size_t)15;
    int2*  binbuf   = (int2*)a16;                            // [E] (key, w)
    int2*  csr_pad  = (int2*)(binbuf + E);                   // [E + NBINS*PADSLACK + 16]
    size_t pk = (size_t)(csr_pad + E + (size_t)NBINS * PADSLACK + 16);
    unsigned short* p11h = (unsigned short*)pk;              // 4096 each for 64x64
    unsigned short* p11l = p11h + 4096;
    unsigned short* p12h = p11l + 4096;
    unsigned short* p12l = p12h + 4096;
    unsigned short* p21h = p12l + 4096;                      // 8192 for 64x128
    unsigned short* p21l = p21h + 8192;
    unsigned short* p22h = p21l + 8192;                      // 8192 for 128x64
    unsigned short* p22l = p22h + 8192;
    unsigned short* p31h = p22l + 8192;
    unsigned short* p31l = p31h + 4096;
    unsigned short* p32h = p31l + 4096;
    unsigned short* p32l = p32h + 4096;
    float* outF = (float*)d_out;                             // [N*64]

    const int n4   = N * 16;
    const int gCvt = (n4 + 255) / 256;
    const int gMlp = (N + 15) / 16;            // 6250 blocks, 25000 waves
    const int gPre = gCvt + NBLK + 128;

    // ---- pre: cvt + histogram + weight pack (one launch) ----
    k_pre<<<gPre, 256, 0, stream>>>((const float4*)x, (ushort4*)xb0, n4, gCvt,
                                    dsti, counts, E, NBINS,
                                    w11, w12, w21, w22, w31, w32,
                                    p11h, p11l, p12h, p12l, p21h, p21l,
                                    p22h, p22l, p31h, p31l, p32h, p32l);
    // ---- CSR build (padded) ----
    k_scanA2 <<<NBINS, 256, 0, stream>>>(counts, bintotal, NBINS);
    k_place2 <<<NBLK,  256, 0, stream>>>(srci, dsti, ew, counts, bintotal,
                                         binstart, binbuf, E, NBINS);
    k_binsort<<<NBINS, 256, 0, stream>>>(binbuf, binstart, pbeg, pend,
                                         csr_pad, N);

    // ---- fused layers (double-buffered activations) ----
    k_fused<64,  true,  true ><<<gMlp, 256, 0, stream>>>(xb0, xb1, pbeg, pend, csr_pad,
                                                         p11h, p11l, b11, p12h, p12l, b12, N);
    k_fused<128, true,  true ><<<gMlp, 256, 0, stream>>>(xb1, xb0, pbeg, pend, csr_pad,
                                                         p21h, p21l, b21, p22h, p22l, b22, N);
    k_fused<64,  false, false><<<gMlp, 256, 0, stream>>>(xb0, outF, pbeg, pend, csr_pad,
                                                         p31h, p31l, b31, p32h, p32l, b32, N);
}